// Round 4
// baseline (802.696 us; speedup 1.0000x reference)
//
#include <hip/hip_runtime.h>
#include <math.h>

#define HID 128
#define EDGE_D 32
#define SC 0.36067376f  // 0.25 * log2(e)

typedef unsigned short u16;
typedef unsigned int u32;
typedef __bf16 bf16x8 __attribute__((ext_vector_type(8)));
typedef float f32x4 __attribute__((ext_vector_type(4)));
typedef u32 u32x4 __attribute__((ext_vector_type(4)));
typedef u32 u32x2 __attribute__((ext_vector_type(2)));

static __device__ __forceinline__ u16 f2bf(float f) {
  u32 u = __float_as_uint(f);
  u += 0x7fffu + ((u >> 16) & 1u);
  return (u16)(u >> 16);
}
static __device__ __forceinline__ float bf2f(u16 b) {
  return __uint_as_float(((u32)b) << 16);
}
// all-lanes sum within each 16-lane row via DPP row rotates (pure VALU)
static __device__ __forceinline__ float grp16_sum(float x) {
  x += __int_as_float(__builtin_amdgcn_mov_dpp(__float_as_int(x), 0x128, 0xf, 0xf, true));
  x += __int_as_float(__builtin_amdgcn_mov_dpp(__float_as_int(x), 0x124, 0xf, 0xf, true));
  x += __int_as_float(__builtin_amdgcn_mov_dpp(__float_as_int(x), 0x122, 0xf, 0xf, true));
  x += __int_as_float(__builtin_amdgcn_mov_dpp(__float_as_int(x), 0x121, 0xf, 0xf, true));
  return x;
}
static __device__ __forceinline__ float wave_allreduce_sum(float v) {
#pragma unroll
  for (int off = 32; off > 0; off >>= 1) v += __shfl_xor(v, off);
  return v;
}

// ---------- LayerNorm: out_bf16 = LN(in) ----------
__global__ __launch_bounds__(256) void ln_kernel(const float* __restrict__ in,
                                                 u16* __restrict__ out,
                                                 const float* __restrict__ w,
                                                 const float* __restrict__ b, int n) {
  int row0 = blockIdx.x * 4 + (threadIdx.x >> 6);
  int lane = threadIdx.x & 63;
  int stride = gridDim.x * 4;
  for (int row = row0; row < n; row += stride) {
    const float* p = in + (size_t)row * HID;
    float a = p[lane], c = p[lane + 64];
    float s = wave_allreduce_sum(a + c);
    float s2 = wave_allreduce_sum(a * a + c * c);
    float mean = s * (1.f / 128.f);
    float var = s2 * (1.f / 128.f) - mean * mean;
    float rs = rsqrtf(var + 1e-5f);
    u16* o = out + (size_t)row * HID;
    o[lane] = f2bf((a - mean) * rs * w[lane] + b[lane]);
    o[lane + 64] = f2bf((c - mean) * rs * w[lane + 64] + b[lane + 64]);
  }
}

// ---------- finalize conv + LN2: x1 = x + msg + skip ; h2_bf16 = LN(x1) ----------
__global__ __launch_bounds__(256) void finalize1_kernel(
    const float* __restrict__ x, const float* __restrict__ msg,
    const float* __restrict__ skip, const float* __restrict__ w,
    const float* __restrict__ b, float* __restrict__ x1, u16* __restrict__ h2,
    int n) {
  int row0 = blockIdx.x * 4 + (threadIdx.x >> 6);
  int lane = threadIdx.x & 63;
  int stride = gridDim.x * 4;
  for (int row = row0; row < n; row += stride) {
    size_t base = (size_t)row * HID;
    float a = x[base + lane] + msg[base + lane] + skip[base + lane];
    float c = x[base + 64 + lane] + msg[base + 64 + lane] + skip[base + 64 + lane];
    x1[base + lane] = a;
    x1[base + 64 + lane] = c;
    float s = wave_allreduce_sum(a + c);
    float s2 = wave_allreduce_sum(a * a + c * c);
    float mean = s * (1.f / 128.f);
    float var = s2 * (1.f / 128.f) - mean * mean;
    float rs = rsqrtf(var + 1e-5f);
    h2[base + lane] = f2bf((a - mean) * rs * w[lane] + b[lane]);
    h2[base + 64 + lane] = f2bf((c - mean) * rs * w[lane + 64] + b[lane + 64]);
  }
}

// ---------- weight conversion: f32 -> transposed bf16 [M][K] ----------
__global__ __launch_bounds__(256) void convert_weights(
    const float* __restrict__ Wq, const float* __restrict__ Wk,
    const float* __restrict__ Wv, const float* __restrict__ Ws,
    const float* __restrict__ W1, const float* __restrict__ W2,
    u16* __restrict__ WqkvsT, u16* __restrict__ W1T, u16* __restrict__ W2T) {
  int idx = blockIdx.x * 256 + threadIdx.x;
  if (idx < 65536) {
    int m = idx >> 7, k = idx & 127;
    const float* Wm = m < 128 ? Wq : m < 256 ? Wk : m < 384 ? Wv : Ws;
    WqkvsT[idx] = f2bf(Wm[k * 128 + (m & 127)]);
  } else if (idx < 131072) {
    int j = idx - 65536;
    int m = j >> 7, k = j & 127;
    W1T[j] = f2bf(W1[k * 512 + m]);
  } else if (idx < 196608) {
    int j = idx - 131072;
    int m = j >> 9, k = j & 511;
    W2T[j] = f2bf(W2[k * 128 + m]);
  }
}

// ---------- bf16 MFMA GEMM: tile 128x128, 4 waves, 16x16x32, direct-to-LDS staging ----------
// A [n][K] bf16, Bt [M][K] bf16. EPI: 0=Q f32 | K/V packed u32x2 | skip f32, 1=GELU->bf16, 2=+bias+add->f32
template <int EPI>
__global__ __launch_bounds__(256) void gemm_bf16(
    const u16* __restrict__ A, const u16* __restrict__ Bt, int n, int K,
    const float* __restrict__ bias0, const float* __restrict__ bias1,
    const float* __restrict__ bias2, const float* __restrict__ bias3,
    float* __restrict__ of0, u32* __restrict__ pkv, u16* __restrict__ ob1,
    float* __restrict__ of3, const float* __restrict__ addsrc) {
  __shared__ u16 As[128 * 32];
  __shared__ u16 Bs[128 * 32];
  int t = threadIdx.x;
  int w = t >> 6, lane = t & 63;
  int g = lane >> 4, sr = lane & 15;
  int r0 = blockIdx.x * 128;
  int c0 = blockIdx.y * 128;
  f32x4 acc[2][8];
#pragma unroll
  for (int m = 0; m < 2; m++)
#pragma unroll
    for (int nn = 0; nn < 8; nn++) acc[m][nn] = {0.f, 0.f, 0.f, 0.f};

  for (int kc = 0; kc < K; kc += 32) {
    __syncthreads();
#pragma unroll
    for (int i = 0; i < 2; i++) {
      int idx = i * 256 + t;  // row = idx>>2, 16B chunk = idx&3
      int row = idx >> 2, c4 = idx & 3;
      __builtin_amdgcn_global_load_lds(
          (const __attribute__((address_space(1))) u32*)(A + (size_t)(r0 + row) * K + kc + c4 * 8),
          (__attribute__((address_space(3))) u32*)&As[idx * 8], 16, 0, 0);
      __builtin_amdgcn_global_load_lds(
          (const __attribute__((address_space(1))) u32*)(Bt + (size_t)(c0 + row) * K + kc + c4 * 8),
          (__attribute__((address_space(3))) u32*)&Bs[idx * 8], 16, 0, 0);
    }
    __syncthreads();
    bf16x8 a0 = *(const bf16x8*)&As[(w * 32 + sr) * 32 + g * 8];
    bf16x8 a1 = *(const bf16x8*)&As[(w * 32 + 16 + sr) * 32 + g * 8];
#pragma unroll
    for (int nn = 0; nn < 8; nn++) {
      bf16x8 b = *(const bf16x8*)&Bs[(nn * 16 + sr) * 32 + g * 8];
      acc[0][nn] = __builtin_amdgcn_mfma_f32_16x16x32_bf16(a0, b, acc[0][nn], 0, 0, 0);
      acc[1][nn] = __builtin_amdgcn_mfma_f32_16x16x32_bf16(a1, b, acc[1][nn], 0, 0, 0);
    }
  }
  if (EPI == 0 && (blockIdx.y == 1 || blockIdx.y == 2)) {
    // K or V: pack (col, col+64) bf16 pair into one u32, store into pkv[row][64+..]
    const float* bp = blockIdx.y == 1 ? bias1 : bias2;
    int which = blockIdx.y - 1;  // 0 = k word, 1 = v word
#pragma unroll
    for (int m = 0; m < 2; m++) {
#pragma unroll
      for (int nn = 0; nn < 4; nn++) {
#pragma unroll
        for (int j = 0; j < 4; j++) {
          int row = r0 + w * 32 + m * 16 + g * 4 + j;
          if (row < n) {
            int cj = nn * 16 + sr;
            float vlo = acc[m][nn][j] + bp[cj];
            float vhi = acc[m][nn + 4][j] + bp[cj + 64];
            u32 word = (u32)f2bf(vlo) | ((u32)f2bf(vhi) << 16);
            pkv[((size_t)row << 7) + (cj << 1) + which] = word;
          }
        }
      }
    }
    return;
  }
#pragma unroll
  for (int m = 0; m < 2; m++) {
#pragma unroll
    for (int nn = 0; nn < 8; nn++) {
#pragma unroll
      for (int j = 0; j < 4; j++) {
        int row = r0 + w * 32 + m * 16 + g * 4 + j;
        if (row < n) {
          int cj = nn * 16 + sr;
          float val = acc[m][nn][j];
          if (EPI == 0) {
            const float* bp = blockIdx.y == 0 ? bias0 : bias3;
            float v2 = val + bp[cj];
            size_t o = (size_t)row * HID + cj;
            if (blockIdx.y == 0) of0[o] = v2;
            else of3[o] = v2;
          } else if (EPI == 1) {
            int cjg = blockIdx.y * 128 + cj;
            float v2 = val + bias0[cjg];
            v2 = 0.5f * v2 * (1.f + erff(v2 * 0.70710678118f));
            ob1[(size_t)row * 512 + cjg] = f2bf(v2);
          } else {
            float v2 = val + bias0[cj] + addsrc[(size_t)row * HID + cj];
            of0[(size_t)row * HID + cj] = v2;
          }
        }
      }
    }
  }
}

// ---------- counting sort by dst ----------
__global__ __launch_bounds__(256) void hist_kernel(const int* __restrict__ dstp,
                                                   int* __restrict__ cnt, int E) {
  int i = blockIdx.x * blockDim.x + threadIdx.x;
  int stride = gridDim.x * blockDim.x;
  for (; i < E; i += stride) atomicAdd(&cnt[dstp[i]], 1);
}

__global__ __launch_bounds__(256) void scan_partial(const int* __restrict__ cnt,
                                                    int* __restrict__ bs, int N) {
  __shared__ int sd[256];
  int idx = blockIdx.x * 256 + threadIdx.x;
  sd[threadIdx.x] = (idx < N) ? cnt[idx] : 0;
  __syncthreads();
  for (int s = 128; s > 0; s >>= 1) {
    if (threadIdx.x < s) sd[threadIdx.x] += sd[threadIdx.x + s];
    __syncthreads();
  }
  if (threadIdx.x == 0) bs[blockIdx.x] = sd[0];
}

__global__ __launch_bounds__(256) void scan_bs(const int* __restrict__ bs,
                                               int* __restrict__ bs2, int nb) {
  __shared__ int sd[256];
  int t = threadIdx.x;
  int v = (t < nb) ? bs[t] : 0;
  sd[t] = v;
  __syncthreads();
  for (int s = 1; s < 256; s <<= 1) {
    int add = (t >= s) ? sd[t - s] : 0;
    __syncthreads();
    sd[t] += add;
    __syncthreads();
  }
  bs2[t] = sd[t] - v;  // exclusive
}

__global__ __launch_bounds__(256) void scan_final(const int* __restrict__ cnt,
                                                  const int* __restrict__ bs2,
                                                  int* __restrict__ offs,
                                                  int* __restrict__ woff, int N) {
  __shared__ int sd[256];
  int t = threadIdx.x;
  int idx = blockIdx.x * 256 + t;
  int v = (idx < N) ? cnt[idx] : 0;
  sd[t] = v;
  __syncthreads();
  for (int s = 1; s < 256; s <<= 1) {
    int add = (t >= s) ? sd[t - s] : 0;
    __syncthreads();
    sd[t] += add;
    __syncthreads();
  }
  if (idx < N) {
    int ex = sd[t] - v + bs2[blockIdx.x];
    offs[idx] = ex;
    woff[idx] = ex;
  }
}

__global__ __launch_bounds__(256) void scatter_kernel(const int* __restrict__ ei,
                                                      int* __restrict__ woff,
                                                      int2* __restrict__ sorted,
                                                      int E) {
  int i = blockIdx.x * blockDim.x + threadIdx.x;
  int stride = gridDim.x * blockDim.x;
  for (; i < E; i += stride) {
    int src = ei[i];
    int dst = ei[E + i];
    int pos = atomicAdd(&woff[dst], 1);
    sorted[pos] = make_int2(src, i);
  }
}

// ---------- qWe precompute ----------
__global__ __launch_bounds__(256) void qwe_kernel(const float* __restrict__ q,
                                                  const float* __restrict__ We,
                                                  const float* __restrict__ be,
                                                  float* __restrict__ qwe,
                                                  float* __restrict__ qbe, int Nn) {
  __shared__ float sWe[32][129];
  __shared__ float sbe[128];
  int t = threadIdx.x;
  for (int i = t; i < 32 * 128; i += 256) sWe[i >> 7][i & 127] = We[i];
  if (t < 128) sbe[t] = be[t];
  __syncthreads();
  int lane = t & 63, w = t >> 6;
  int g = lane >> 4, sr = lane & 15;
  int node = blockIdx.x * 4 + w;
  if (node >= Nn) return;
  float q0 = q[(size_t)node * HID + lane];
  float q1 = q[(size_t)node * HID + lane + 64];
  float o00 = 0.f, o01 = 0.f, o10 = 0.f, o11 = 0.f;
  int base = lane & 48;
#pragma unroll
  for (int d0 = 0; d0 < 16; d0++) {
    float qa = __shfl(q0, base + d0);
    float qb = __shfl(q1, base + d0);
    int col = base + d0;
    o00 += qa * sWe[2 * sr][col];
    o01 += qa * sWe[2 * sr + 1][col];
    o10 += qb * sWe[2 * sr][64 + col];
    o11 += qb * sWe[2 * sr + 1][64 + col];
  }
  float* qwn = qwe + (size_t)node * 256;
  qwn[g * 32 + 2 * sr] = o00 * SC;
  qwn[g * 32 + 2 * sr + 1] = o01 * SC;
  qwn[(4 + g) * 32 + 2 * sr] = o10 * SC;
  qwn[(4 + g) * 32 + 2 * sr + 1] = o11 * SC;
  float t0 = grp16_sum(q0 * sbe[lane]);
  float t1 = grp16_sum(q1 * sbe[lane + 64]);
  if (sr == 0) {
    qbe[node * 8 + g] = t0 * SC;
    qbe[node * 8 + 4 + g] = t1 * SC;
  }
}

// ---------- fused edge attention: 1 wave/node, NO-max softmax (shift-invariant, |p|<~20) ----------
__global__ __launch_bounds__(256) void fused_edge(
    const int* __restrict__ offs, const int* __restrict__ cnt,
    const int2* __restrict__ sorted, const float* __restrict__ ea,
    const float* __restrict__ We, const float* __restrict__ be,
    const float* __restrict__ q, const u32* __restrict__ pkv,
    const float* __restrict__ qwe, const float* __restrict__ qbe,
    float* __restrict__ msg, int Nn) {
  int lane = threadIdx.x & 63;
  int w = threadIdx.x >> 6;
  int g = lane >> 4, sr = lane & 15;
  int wid = blockIdx.x * 4 + w;
  int nw = gridDim.x * 4;
  int per = (Nn + nw - 1) / nw;
  int n0 = wid * per;
  int n1 = min(Nn, n0 + per);
  if (n0 >= n1) return;

  float be0 = be[lane], be1 = be[lane + 64];

  for (int node = n0; node < n1; node++) {
    int beg = offs[node], num = cnt[node];
    size_t qb_ = (size_t)node * HID + lane;
    if (num == 0) {
      msg[qb_] = 0.f;
      msg[qb_ + 64] = 0.f;
      continue;
    }
    float q0 = q[qb_] * SC, q1 = q[qb_ + 64] * SC;
    const float* qwn = qwe + (size_t)node * 256;
    float2 qw0 = *(const float2*)(qwn + g * 32 + 2 * sr);
    float2 qw1 = *(const float2*)(qwn + (4 + g) * 32 + 2 * sr);
    float qb0 = qbe[node * 8 + g], qb1 = qbe[node * 8 + 4 + g];

    float l1 = 0.f, l2 = 0.f, a0 = 0.f, a1 = 0.f;
    float wa00 = 0.f, wa01 = 0.f, wa10 = 0.f, wa11 = 0.f;

    int2 sc = sorted[beg];
    u32x2 kvc = *(const u32x2*)(pkv + ((size_t)sc.x << 7) + (lane << 1));
    float2 eac = *(const float2*)(ea + ((size_t)sc.y << 5) + 2 * sr);

    for (int i = 0; i < num; i++) {
      u32x2 kvn = {0, 0};
      float2 ean = make_float2(0.f, 0.f);
      if (i + 1 < num) {  // prefetch next edge
        int2 sn = sorted[beg + i + 1];
        kvn = *(const u32x2*)(pkv + ((size_t)sn.x << 7) + (lane << 1));
        ean = *(const float2*)(ea + ((size_t)sn.y << 5) + 2 * sr);
      }
      float k0 = __uint_as_float(kvc.x << 16);
      float k1 = __uint_as_float(kvc.x & 0xffff0000u);
      float v0 = __uint_as_float(kvc.y << 16);
      float v1 = __uint_as_float(kvc.y & 0xffff0000u);
      float p0 = fmaf(q0, k0, fmaf(qw0.x, eac.x, qw0.y * eac.y));
      float p1 = fmaf(q1, k1, fmaf(qw1.x, eac.x, qw1.y * eac.y));
      p0 = grp16_sum(p0) + qb0;
      p1 = grp16_sum(p1) + qb1;
      float w1 = __builtin_amdgcn_exp2f(p0);
      float w2 = __builtin_amdgcn_exp2f(p1);
      l1 += w1;
      l2 += w2;
      a0 = fmaf(w1, v0, a0);
      a1 = fmaf(w2, v1, a1);
      wa00 = fmaf(w1, eac.x, wa00);
      wa01 = fmaf(w1, eac.y, wa01);
      wa10 = fmaf(w2, eac.x, wa10);
      wa11 = fmaf(w2, eac.y, wa11);
      kvc = kvn;
      eac = ean;
    }
    // recombine e-part once per node: msg_d += sum_j We[j][d] * wea[h(d)][j] + be_d*l
    float acc0 = be0 * l1, acc1 = be1 * l2;
    int base = lane & 48;
#pragma unroll
    for (int jj = 0; jj < 16; jj++) {
      float wa = __shfl(wa00, base + jj);
      float wb = __shfl(wa01, base + jj);
      acc0 += We[2 * jj * HID + lane] * wa + We[(2 * jj + 1) * HID + lane] * wb;
      float wc = __shfl(wa10, base + jj);
      float wd = __shfl(wa11, base + jj);
      acc1 += We[2 * jj * HID + 64 + lane] * wc + We[(2 * jj + 1) * HID + 64 + lane] * wd;
    }
    msg[qb_] = (a0 + acc0) / (l1 + 1e-16f);
    msg[qb_ + 64] = (a1 + acc1) / (l2 + 1e-16f);
  }
}

extern "C" void kernel_launch(void* const* d_in, const int* in_sizes, int n_in,
                              void* d_out, int out_size, void* d_ws, size_t ws_size,
                              hipStream_t stream) {
  const float* x = (const float*)d_in[0];
  const int* ei = (const int*)d_in[1];
  const float* ea = (const float*)d_in[2];
  const float* Wq = (const float*)d_in[3];
  const float* bq = (const float*)d_in[4];
  const float* Wk = (const float*)d_in[5];
  const float* bk = (const float*)d_in[6];
  const float* Wv = (const float*)d_in[7];
  const float* bv = (const float*)d_in[8];
  const float* We = (const float*)d_in[9];
  const float* be = (const float*)d_in[10];
  const float* Wskip = (const float*)d_in[11];
  const float* bskip = (const float*)d_in[12];
  const float* ln1w = (const float*)d_in[13];
  const float* ln1b = (const float*)d_in[14];
  const float* W1 = (const float*)d_in[15];
  const float* b1p = (const float*)d_in[16];
  const float* W2 = (const float*)d_in[17];
  const float* b2p = (const float*)d_in[18];
  const float* ln2w = (const float*)d_in[19];
  const float* ln2b = (const float*)d_in[20];

  int N = in_sizes[0] / HID;
  int E = in_sizes[1] / 2;
  size_t nf = (size_t)N * HID;

  float* ws = (float*)d_ws;
  size_t off = 0;
  u16* h_bf = (u16*)(ws + off); off += nf / 2;
  float* q = ws + off; off += nf;
  u32* pkv = (u32*)(ws + off); off += nf;  // [node][64]{kword,vword}
  float* skip = ws + off; off += nf;
  float* x1 = ws + off; off += nf;
  u16* h2bf = (u16*)(ws + off); off += nf / 2;
  float* msg = ws + off; off += nf;
  float* qwe = ws + off; off += (size_t)N * 256;  // aliased by tbf later
  float* qbe = ws + off; off += (size_t)N * 8;
  int2* sorted = (int2*)(ws + off); off += (size_t)E * 2;
  int* cnt = (int*)(ws + off); off += N;
  int* offs = (int*)(ws + off); off += N;
  int* woff = (int*)(ws + off); off += N;
  int* bs = (int*)(ws + off); off += 256;
  int* bs2 = (int*)(ws + off); off += 256;
  u16* WqkvsT = (u16*)(ws + off); off += 32768;
  u16* W1T = (u16*)(ws + off); off += 32768;
  u16* W2T = (u16*)(ws + off); off += 32768;
  u16* tbf = (u16*)qwe;  // FFN intermediate aliases qwe (dead after fused_edge)

  hipMemsetAsync(cnt, 0, (size_t)N * sizeof(int), stream);
  convert_weights<<<768, 256, 0, stream>>>(Wq, Wk, Wv, Wskip, W1, W2, WqkvsT, W1T, W2T);

  int ln_blocks = (N + 3) / 4;
  ln_kernel<<<ln_blocks, 256, 0, stream>>>(x, h_bf, ln1w, ln1b, N);

  dim3 gq((N + 127) / 128, 4);
  gemm_bf16<0><<<gq, 256, 0, stream>>>(h_bf, WqkvsT, N, 128, bq, bk, bv, bskip,
                                       q, pkv, nullptr, skip, nullptr);

  int nb = (N + 255) / 256;
  hist_kernel<<<1024, 256, 0, stream>>>(ei + E, cnt, E);
  scan_partial<<<nb, 256, 0, stream>>>(cnt, bs, N);
  scan_bs<<<1, 256, 0, stream>>>(bs, bs2, nb);
  scan_final<<<nb, 256, 0, stream>>>(cnt, bs2, offs, woff, N);
  scatter_kernel<<<1024, 256, 0, stream>>>(ei, woff, sorted, E);

  qwe_kernel<<<(N + 3) / 4, 256, 0, stream>>>(q, We, be, qwe, qbe, N);

  fused_edge<<<4096, 256, 0, stream>>>(offs, cnt, sorted, ea, We, be, q, pkv,
                                       qwe, qbe, msg, N);

  finalize1_kernel<<<ln_blocks, 256, 0, stream>>>(x, msg, skip, ln2w, ln2b, x1, h2bf, N);

  dim3 gf1((N + 127) / 128, 4);
  gemm_bf16<1><<<gf1, 256, 0, stream>>>(h2bf, W1T, N, 128, b1p, nullptr, nullptr,
                                        nullptr, nullptr, nullptr, tbf, nullptr, nullptr);
  dim3 gf2((N + 127) / 128, 1);
  gemm_bf16<2><<<gf2, 256, 0, stream>>>(tbf, W2T, N, 512, b2p, nullptr, nullptr,
                                        nullptr, (float*)d_out, nullptr, nullptr,
                                        nullptr, x1);
}

// Round 5
// 488.736 us; speedup vs baseline: 1.6424x; 1.6424x over previous
//
#include <hip/hip_runtime.h>
#include <math.h>

#define HID 128
#define EDGE_D 32
#define SC 0.36067376f  // 0.25 * log2(e)

typedef unsigned short u16;
typedef unsigned int u32;
typedef __bf16 bf16x8 __attribute__((ext_vector_type(8)));
typedef float f32x4 __attribute__((ext_vector_type(4)));
typedef u32 u32x4 __attribute__((ext_vector_type(4)));
typedef u32 u32x2 __attribute__((ext_vector_type(2)));

static __device__ __forceinline__ u16 f2bf(float f) {
  u32 u = __float_as_uint(f);
  u += 0x7fffu + ((u >> 16) & 1u);
  return (u16)(u >> 16);
}
// all-lanes sum within each 16-lane row via DPP row rotates (pure VALU)
static __device__ __forceinline__ float grp16_sum(float x) {
  x += __int_as_float(__builtin_amdgcn_mov_dpp(__float_as_int(x), 0x128, 0xf, 0xf, true));
  x += __int_as_float(__builtin_amdgcn_mov_dpp(__float_as_int(x), 0x124, 0xf, 0xf, true));
  x += __int_as_float(__builtin_amdgcn_mov_dpp(__float_as_int(x), 0x122, 0xf, 0xf, true));
  x += __int_as_float(__builtin_amdgcn_mov_dpp(__float_as_int(x), 0x121, 0xf, 0xf, true));
  return x;
}
static __device__ __forceinline__ float wave_allreduce_sum(float v) {
#pragma unroll
  for (int off = 32; off > 0; off >>= 1) v += __shfl_xor(v, off);
  return v;
}

// ---------- LayerNorm: out_bf16 = LN(in) ----------
__global__ __launch_bounds__(256) void ln_kernel(const float* __restrict__ in,
                                                 u16* __restrict__ out,
                                                 const float* __restrict__ w,
                                                 const float* __restrict__ b, int n) {
  int row0 = blockIdx.x * 4 + (threadIdx.x >> 6);
  int lane = threadIdx.x & 63;
  int stride = gridDim.x * 4;
  for (int row = row0; row < n; row += stride) {
    const float* p = in + (size_t)row * HID;
    float a = p[lane], c = p[lane + 64];
    float s = wave_allreduce_sum(a + c);
    float s2 = wave_allreduce_sum(a * a + c * c);
    float mean = s * (1.f / 128.f);
    float var = s2 * (1.f / 128.f) - mean * mean;
    float rs = rsqrtf(var + 1e-5f);
    u16* o = out + (size_t)row * HID;
    o[lane] = f2bf((a - mean) * rs * w[lane] + b[lane]);
    o[lane + 64] = f2bf((c - mean) * rs * w[lane + 64] + b[lane + 64]);
  }
}

// ---------- finalize conv + LN2 ----------
// x1 = x + (msg + msgE)/l + be + skip  (written in-place over skip); h2_bf16 = LN(x1)
__global__ __launch_bounds__(256) void finalize1_kernel(
    const float* __restrict__ x, const float* __restrict__ msg,
    const float* __restrict__ msgE, const float* __restrict__ lbuf,
    const float* __restrict__ be, float* __restrict__ skipx1,
    const float* __restrict__ w, const float* __restrict__ b,
    u16* __restrict__ h2, int n) {
  int row0 = blockIdx.x * 4 + (threadIdx.x >> 6);
  int lane = threadIdx.x & 63;
  int stride = gridDim.x * 4;
  float be0 = be[lane], be1 = be[lane + 64];
  for (int row = row0; row < n; row += stride) {
    size_t base = (size_t)row * HID;
    float inv0 = 1.f / (lbuf[(size_t)row * 8 + (lane >> 4)] + 1e-30f);
    float inv1 = 1.f / (lbuf[(size_t)row * 8 + 4 + (lane >> 4)] + 1e-30f);
    float a = x[base + lane] + (msg[base + lane] + msgE[base + lane]) * inv0 + be0 +
              skipx1[base + lane];
    float c = x[base + 64 + lane] + (msg[base + 64 + lane] + msgE[base + 64 + lane]) * inv1 +
              be1 + skipx1[base + 64 + lane];
    skipx1[base + lane] = a;
    skipx1[base + 64 + lane] = c;
    float s = wave_allreduce_sum(a + c);
    float s2 = wave_allreduce_sum(a * a + c * c);
    float mean = s * (1.f / 128.f);
    float var = s2 * (1.f / 128.f) - mean * mean;
    float rs = rsqrtf(var + 1e-5f);
    h2[base + lane] = f2bf((a - mean) * rs * w[lane] + b[lane]);
    h2[base + 64 + lane] = f2bf((c - mean) * rs * w[lane + 64] + b[lane + 64]);
  }
}

// ---------- weight conversion: f32 -> transposed bf16 [M][K]; + block-diag We^T ----------
__global__ __launch_bounds__(256) void convert_weights(
    const float* __restrict__ Wq, const float* __restrict__ Wk,
    const float* __restrict__ Wv, const float* __restrict__ Ws,
    const float* __restrict__ W1, const float* __restrict__ W2,
    const float* __restrict__ We, u16* __restrict__ WqkvsT,
    u16* __restrict__ W1T, u16* __restrict__ W2T, u16* __restrict__ WbdT) {
  int idx = blockIdx.x * 256 + threadIdx.x;
  if (idx < 65536) {
    int m = idx >> 7, k = idx & 127;
    const float* Wm = m < 128 ? Wq : m < 256 ? Wk : m < 384 ? Wv : Ws;
    WqkvsT[idx] = f2bf(Wm[k * 128 + (m & 127)]);
  } else if (idx < 131072) {
    int j = idx - 65536;
    int m = j >> 7, k = j & 127;
    W1T[j] = f2bf(W1[k * 512 + m]);
  } else if (idx < 196608) {
    int j = idx - 131072;
    int m = j >> 9, k = j & 511;
    W2T[j] = f2bf(W2[k * 128 + m]);
  } else if (idx < 229376) {
    int j = idx - 196608;  // WbdT [128][256]: (m, c) ; We_bd^T
    int m = j >> 8, c = j & 255;
    WbdT[j] = ((c >> 5) == (m >> 4)) ? f2bf(We[(c & 31) * 128 + m]) : (u16)0;
  }
}

// ---------- bf16 MFMA GEMM: tile 128x128, 4 waves, 16x16x32, direct-to-LDS staging ----------
// EPI: 0=Q f32 | K/V packed u32x2 | skip f32 ; 1=GELU->bf16 ; 2=+bias+add->f32 ; 3=plain f32
template <int EPI>
__global__ __launch_bounds__(256) void gemm_bf16(
    const u16* __restrict__ A, const u16* __restrict__ Bt, int n, int K,
    const float* __restrict__ bias0, const float* __restrict__ bias1,
    const float* __restrict__ bias2, const float* __restrict__ bias3,
    float* __restrict__ of0, u32* __restrict__ pkv, u16* __restrict__ ob1,
    float* __restrict__ of3, const float* __restrict__ addsrc) {
  __shared__ u16 As[128 * 32];
  __shared__ u16 Bs[128 * 32];
  int t = threadIdx.x;
  int w = t >> 6, lane = t & 63;
  int g = lane >> 4, sr = lane & 15;
  int r0 = blockIdx.x * 128;
  int c0 = blockIdx.y * 128;
  f32x4 acc[2][8];
#pragma unroll
  for (int m = 0; m < 2; m++)
#pragma unroll
    for (int nn = 0; nn < 8; nn++) acc[m][nn] = {0.f, 0.f, 0.f, 0.f};

  for (int kc = 0; kc < K; kc += 32) {
    __syncthreads();
#pragma unroll
    for (int i = 0; i < 2; i++) {
      int idx = i * 256 + t;  // row = idx>>2, 16B chunk = idx&3
      int row = idx >> 2, c4 = idx & 3;
      __builtin_amdgcn_global_load_lds(
          (const __attribute__((address_space(1))) u32*)(A + (size_t)(r0 + row) * K + kc + c4 * 8),
          (__attribute__((address_space(3))) u32*)&As[idx * 8], 16, 0, 0);
      __builtin_amdgcn_global_load_lds(
          (const __attribute__((address_space(1))) u32*)(Bt + (size_t)(c0 + row) * K + kc + c4 * 8),
          (__attribute__((address_space(3))) u32*)&Bs[idx * 8], 16, 0, 0);
    }
    __syncthreads();
    bf16x8 a0 = *(const bf16x8*)&As[(w * 32 + sr) * 32 + g * 8];
    bf16x8 a1 = *(const bf16x8*)&As[(w * 32 + 16 + sr) * 32 + g * 8];
#pragma unroll
    for (int nn = 0; nn < 8; nn++) {
      bf16x8 b = *(const bf16x8*)&Bs[(nn * 16 + sr) * 32 + g * 8];
      acc[0][nn] = __builtin_amdgcn_mfma_f32_16x16x32_bf16(a0, b, acc[0][nn], 0, 0, 0);
      acc[1][nn] = __builtin_amdgcn_mfma_f32_16x16x32_bf16(a1, b, acc[1][nn], 0, 0, 0);
    }
  }
  if (EPI == 0 && (blockIdx.y == 1 || blockIdx.y == 2)) {
    const float* bp = blockIdx.y == 1 ? bias1 : bias2;
    int which = blockIdx.y - 1;  // 0 = k word, 1 = v word
#pragma unroll
    for (int m = 0; m < 2; m++) {
#pragma unroll
      for (int nn = 0; nn < 4; nn++) {
#pragma unroll
        for (int j = 0; j < 4; j++) {
          int row = r0 + w * 32 + m * 16 + g * 4 + j;
          if (row < n) {
            int cj = nn * 16 + sr;
            float vlo = acc[m][nn][j] + bp[cj];
            float vhi = acc[m][nn + 4][j] + bp[cj + 64];
            u32 word = (u32)f2bf(vlo) | ((u32)f2bf(vhi) << 16);
            pkv[((size_t)row << 7) + (cj << 1) + which] = word;
          }
        }
      }
    }
    return;
  }
#pragma unroll
  for (int m = 0; m < 2; m++) {
#pragma unroll
    for (int nn = 0; nn < 8; nn++) {
#pragma unroll
      for (int j = 0; j < 4; j++) {
        int row = r0 + w * 32 + m * 16 + g * 4 + j;
        if (row < n) {
          int cj = nn * 16 + sr;
          float val = acc[m][nn][j];
          if (EPI == 0) {
            const float* bp = blockIdx.y == 0 ? bias0 : bias3;
            float v2 = val + bp[cj];
            size_t o = (size_t)row * HID + cj;
            if (blockIdx.y == 0) of0[o] = v2;
            else of3[o] = v2;
          } else if (EPI == 1) {
            int cjg = blockIdx.y * 128 + cj;
            float v2 = val + bias0[cjg];
            v2 = 0.5f * v2 * (1.f + erff(v2 * 0.70710678118f));
            ob1[(size_t)row * 512 + cjg] = f2bf(v2);
          } else if (EPI == 2) {
            float v2 = val + bias0[cj] + addsrc[(size_t)row * HID + cj];
            of0[(size_t)row * HID + cj] = v2;
          } else {
            of0[(size_t)row * HID + cj] = val;
          }
        }
      }
    }
  }
}

// ---------- counting sort by dst ----------
__global__ __launch_bounds__(256) void hist_kernel(const int* __restrict__ dstp,
                                                   int* __restrict__ cnt, int E) {
  int i = blockIdx.x * blockDim.x + threadIdx.x;
  int stride = gridDim.x * blockDim.x;
  for (; i < E; i += stride) atomicAdd(&cnt[dstp[i]], 1);
}

__global__ __launch_bounds__(256) void scan_partial(const int* __restrict__ cnt,
                                                    int* __restrict__ bs, int N) {
  __shared__ int sd[256];
  int idx = blockIdx.x * 256 + threadIdx.x;
  sd[threadIdx.x] = (idx < N) ? cnt[idx] : 0;
  __syncthreads();
  for (int s = 128; s > 0; s >>= 1) {
    if (threadIdx.x < s) sd[threadIdx.x] += sd[threadIdx.x + s];
    __syncthreads();
  }
  if (threadIdx.x == 0) bs[blockIdx.x] = sd[0];
}

__global__ __launch_bounds__(256) void scan_bs(const int* __restrict__ bs,
                                               int* __restrict__ bs2, int nb) {
  __shared__ int sd[256];
  int t = threadIdx.x;
  int v = (t < nb) ? bs[t] : 0;
  sd[t] = v;
  __syncthreads();
  for (int s = 1; s < 256; s <<= 1) {
    int add = (t >= s) ? sd[t - s] : 0;
    __syncthreads();
    sd[t] += add;
    __syncthreads();
  }
  bs2[t] = sd[t] - v;  // exclusive
}

__global__ __launch_bounds__(256) void scan_final(const int* __restrict__ cnt,
                                                  const int* __restrict__ bs2,
                                                  int* __restrict__ offs,
                                                  int* __restrict__ woff, int N) {
  __shared__ int sd[256];
  int t = threadIdx.x;
  int idx = blockIdx.x * 256 + t;
  int v = (idx < N) ? cnt[idx] : 0;
  sd[t] = v;
  __syncthreads();
  for (int s = 1; s < 256; s <<= 1) {
    int add = (t >= s) ? sd[t - s] : 0;
    __syncthreads();
    sd[t] += add;
    __syncthreads();
  }
  if (idx < N) {
    int ex = sd[t] - v + bs2[blockIdx.x];
    offs[idx] = ex;
    woff[idx] = ex;
  }
}

__global__ __launch_bounds__(256) void scatter_kernel(const int* __restrict__ ei,
                                                      int* __restrict__ woff,
                                                      int2* __restrict__ sorted,
                                                      int E) {
  int i = blockIdx.x * blockDim.x + threadIdx.x;
  int stride = gridDim.x * blockDim.x;
  for (; i < E; i += stride) {
    int src = ei[i];
    int dst = ei[E + i];
    int pos = atomicAdd(&woff[dst], 1);
    sorted[pos] = make_int2(src, i);
  }
}

// ---------- qWe precompute ----------
__global__ __launch_bounds__(256) void qwe_kernel(const float* __restrict__ q,
                                                  const float* __restrict__ We,
                                                  const float* __restrict__ be,
                                                  float* __restrict__ qwe,
                                                  float* __restrict__ qbe, int Nn) {
  __shared__ float sWe[32][129];
  __shared__ float sbe[128];
  int t = threadIdx.x;
  for (int i = t; i < 32 * 128; i += 256) sWe[i >> 7][i & 127] = We[i];
  if (t < 128) sbe[t] = be[t];
  __syncthreads();
  int lane = t & 63, w = t >> 6;
  int g = lane >> 4, sr = lane & 15;
  int node = blockIdx.x * 4 + w;
  if (node >= Nn) return;
  float q0 = q[(size_t)node * HID + lane];
  float q1 = q[(size_t)node * HID + lane + 64];
  float o00 = 0.f, o01 = 0.f, o10 = 0.f, o11 = 0.f;
  int base = lane & 48;
#pragma unroll
  for (int d0 = 0; d0 < 16; d0++) {
    float qa = __shfl(q0, base + d0);
    float qb = __shfl(q1, base + d0);
    int col = base + d0;
    o00 += qa * sWe[2 * sr][col];
    o01 += qa * sWe[2 * sr + 1][col];
    o10 += qb * sWe[2 * sr][64 + col];
    o11 += qb * sWe[2 * sr + 1][64 + col];
  }
  float* qwn = qwe + (size_t)node * 256;
  qwn[g * 32 + 2 * sr] = o00 * SC;
  qwn[g * 32 + 2 * sr + 1] = o01 * SC;
  qwn[(4 + g) * 32 + 2 * sr] = o10 * SC;
  qwn[(4 + g) * 32 + 2 * sr + 1] = o11 * SC;
  float t0 = grp16_sum(q0 * sbe[lane]);
  float t1 = grp16_sum(q1 * sbe[lane + 64]);
  if (sr == 0) {
    qbe[node * 8 + g] = t0 * SC;
    qbe[node * 8 + 4 + g] = t1 * SC;
  }
}

// ---------- fused edge attention ----------
// 1 wave/node-range; cooperative segment load + readlane addressing; 4-wide double-buffered
// chunk pipeline; no-max softmax (shift-invariant). Outputs unnormalized a, l, wea(bf16).
#define ISSUE4(P, base_)                                                       \
  {                                                                            \
    _Pragma("unroll") for (int jj = 0; jj < 4; jj++) {                         \
      int sj = min(base_ + jj, segn - 1);                                      \
      int sxx = __builtin_amdgcn_readlane(se.x, sj);                           \
      int syy = __builtin_amdgcn_readlane(se.y, sj);                           \
      P##kv[jj] = *(const u32x2*)(pkv + ((size_t)sxx << 7) + (lane << 1));     \
      P##ea[jj] = *(const float2*)(ea + ((size_t)syy << 5) + 2 * sr);          \
    }                                                                          \
  }

#define COMP4(P, base_)                                                        \
  {                                                                            \
    _Pragma("unroll") for (int jj = 0; jj < 4; jj++) {                         \
      u32 kx = P##kv[jj].x, ky = P##kv[jj].y;                                  \
      float2 eaj = P##ea[jj];                                                  \
      float k0 = __uint_as_float(kx << 16);                                    \
      float k1 = __uint_as_float(kx & 0xffff0000u);                            \
      float v0f = __uint_as_float(ky << 16);                                   \
      float v1f = __uint_as_float(ky & 0xffff0000u);                           \
      float p0 = fmaf(q0C, k0, fmaf(qw0C.x, eaj.x, qw0C.y * eaj.y));           \
      float p1 = fmaf(q1C, k1, fmaf(qw1C.x, eaj.x, qw1C.y * eaj.y));           \
      p0 = grp16_sum(p0) + qb0C;                                               \
      p1 = grp16_sum(p1) + qb1C;                                               \
      bool val_ = (base_ + jj) < segn;                                         \
      float w1 = val_ ? __builtin_amdgcn_exp2f(p0) : 0.f;                      \
      float w2 = val_ ? __builtin_amdgcn_exp2f(p1) : 0.f;                      \
      l1 += w1;                                                                \
      l2 += w2;                                                                \
      a0 = fmaf(w1, v0f, a0);                                                  \
      a1 = fmaf(w2, v1f, a1);                                                  \
      wa00 = fmaf(w1, eaj.x, wa00);                                            \
      wa01 = fmaf(w1, eaj.y, wa01);                                            \
      wa10 = fmaf(w2, eaj.x, wa10);                                            \
      wa11 = fmaf(w2, eaj.y, wa11);                                            \
    }                                                                          \
  }

__global__ __launch_bounds__(256) void fused_edge(
    const int* __restrict__ offs, const int* __restrict__ cnt,
    const int2* __restrict__ sorted, const float* __restrict__ ea,
    const float* __restrict__ be, const float* __restrict__ q,
    const u32* __restrict__ pkv, const float* __restrict__ qwe,
    const float* __restrict__ qbe, float* __restrict__ msg,
    u32* __restrict__ weab, float* __restrict__ lbuf, int Nn, int Etot) {
  int lane = threadIdx.x & 63;
  int w = threadIdx.x >> 6;
  int g = lane >> 4, sr = lane & 15;
  int wid = blockIdx.x * 4 + w;
  int nw = gridDim.x * 4;
  int per = (Nn + nw - 1) / nw;
  int n0 = wid * per;
  int n1 = min(Nn, n0 + per);
  if (n0 >= n1) return;
  int nn = n1 - n0;

  float be0 = be[lane], be1 = be[lane + 64];

  // cooperative offs/cnt for the wave's node range (nn <= 64)
  int ml = min(lane, nn - 1);
  int myBeg = offs[n0 + ml];
  int myCnt = cnt[n0 + ml];

  // prefetch node 0 state
  int beg = __builtin_amdgcn_readlane(myBeg, 0);
  int num = __builtin_amdgcn_readlane(myCnt, 0);
  int2 seC = sorted[min(beg + min(lane, max(num - 1, 0)), Etot - 1)];
  size_t qoff = (size_t)n0 * HID + lane;
  float q0C = q[qoff] * SC, q1C = q[qoff + 64] * SC;
  const float* qwn0 = qwe + (size_t)n0 * 256;
  float2 qw0C = *(const float2*)(qwn0 + g * 32 + 2 * sr);
  float2 qw1C = *(const float2*)(qwn0 + (4 + g) * 32 + 2 * sr);
  float qb0C = qbe[(size_t)n0 * 8 + g], qb1C = qbe[(size_t)n0 * 8 + 4 + g];

  for (int ni = 0; ni < nn; ni++) {
    int node = n0 + ni;
    // issue next-node prefetch (independent of current compute)
    int begX = 0, numX = 0;
    int2 seX = make_int2(0, 0);
    float q0X = 0.f, q1X = 0.f, qb0X = 0.f, qb1X = 0.f;
    float2 qw0X = make_float2(0.f, 0.f), qw1X = make_float2(0.f, 0.f);
    if (ni + 1 < nn) {
      begX = __builtin_amdgcn_readlane(myBeg, ni + 1);
      numX = __builtin_amdgcn_readlane(myCnt, ni + 1);
      seX = sorted[min(begX + min(lane, max(numX - 1, 0)), Etot - 1)];
      size_t qoffX = (size_t)(node + 1) * HID + lane;
      q0X = q[qoffX] * SC;
      q1X = q[qoffX + 64] * SC;
      const float* qwnX = qwe + (size_t)(node + 1) * 256;
      qw0X = *(const float2*)(qwnX + g * 32 + 2 * sr);
      qw1X = *(const float2*)(qwnX + (4 + g) * 32 + 2 * sr);
      qb0X = qbe[(size_t)(node + 1) * 8 + g];
      qb1X = qbe[(size_t)(node + 1) * 8 + 4 + g];
    }
    float l1 = 0.f, l2 = 0.f, a0 = 0.f, a1 = 0.f;
    float wa00 = 0.f, wa01 = 0.f, wa10 = 0.f, wa11 = 0.f;
    if (num > 0) {
      int cb = 0;
      int2 se = seC;
      while (true) {
        int segn = min(num - cb, 64);
        u32x2 Akv[4], Bkv[4];
        float2 Aea[4], Bea[4];
        ISSUE4(A, 0)
        for (int c = 0; c < segn; c += 8) {
          ISSUE4(B, c + 4)
          COMP4(A, c)
          ISSUE4(A, c + 8)
          COMP4(B, c + 4)
        }
        cb += 64;
        if (cb >= num) break;
        int rem = num - cb;
        se = sorted[min(beg + cb + min(lane, rem - 1), Etot - 1)];
      }
    }
    // epilogue: store unnormalized a, packed wea (bf16), l
    size_t ob = (size_t)node * HID + lane;
    if (num > 0) {
      msg[ob] = a0;
      msg[ob + 64] = a1;
    } else {  // empty segment: reference msg==0; finalize adds be -> cancel it
      msg[ob] = -be0;
      msg[ob + 64] = -be1;
    }
    u32 wlo = (u32)f2bf(wa00) | ((u32)f2bf(wa01) << 16);
    u32 whi = (u32)f2bf(wa10) | ((u32)f2bf(wa11) << 16);
    weab[(size_t)node * 128 + g * 16 + sr] = wlo;
    weab[(size_t)node * 128 + 64 + g * 16 + sr] = whi;
    if (sr == 0) {
      lbuf[(size_t)node * 8 + g] = (num > 0) ? l1 : 1.f;
      lbuf[(size_t)node * 8 + 4 + g] = (num > 0) ? l2 : 1.f;
    }
    // rotate prefetched state
    beg = begX;
    num = numX;
    seC = seX;
    q0C = q0X; q1C = q1X;
    qw0C = qw0X; qw1C = qw1X;
    qb0C = qb0X; qb1C = qb1X;
  }
}

extern "C" void kernel_launch(void* const* d_in, const int* in_sizes, int n_in,
                              void* d_out, int out_size, void* d_ws, size_t ws_size,
                              hipStream_t stream) {
  const float* x = (const float*)d_in[0];
  const int* ei = (const int*)d_in[1];
  const float* ea = (const float*)d_in[2];
  const float* Wq = (const float*)d_in[3];
  const float* bq = (const float*)d_in[4];
  const float* Wk = (const float*)d_in[5];
  const float* bk = (const float*)d_in[6];
  const float* Wv = (const float*)d_in[7];
  const float* bv = (const float*)d_in[8];
  const float* We = (const float*)d_in[9];
  const float* be = (const float*)d_in[10];
  const float* Wskip = (const float*)d_in[11];
  const float* bskip = (const float*)d_in[12];
  const float* ln1w = (const float*)d_in[13];
  const float* ln1b = (const float*)d_in[14];
  const float* W1 = (const float*)d_in[15];
  const float* b1p = (const float*)d_in[16];
  const float* W2 = (const float*)d_in[17];
  const float* b2p = (const float*)d_in[18];
  const float* ln2w = (const float*)d_in[19];
  const float* ln2b = (const float*)d_in[20];

  int N = in_sizes[0] / HID;
  int E = in_sizes[1] / 2;
  size_t nf = (size_t)N * HID;

  float* ws = (float*)d_ws;
  size_t off = 0;
  u16* h_bf = (u16*)(ws + off); off += nf / 2;
  float* q = ws + off; off += nf;        // aliased by msgE after fused_edge
  u32* pkv = (u32*)(ws + off); off += nf;  // [node][64]{kword,vword}
  float* skipx1 = ws + off; off += nf;   // skip, overwritten in-place with x1
  u16* h2bf = (u16*)(ws + off); off += nf / 2;
  float* msg = ws + off; off += nf;
  u32* weab = (u32*)(ws + off); off += nf;  // [node][128] packed bf16 pairs
  float* lbuf = ws + off; off += (size_t)N * 8;
  float* qwe = ws + off; off += (size_t)N * 256;  // aliased by tbf in FFN
  float* qbe = ws + off; off += (size_t)N * 8;
  int2* sorted = (int2*)(ws + off); off += (size_t)E * 2;
  int* cnt = (int*)(ws + off); off += N;
  int* offs = (int*)(ws + off); off += N;
  int* woff = (int*)(ws + off); off += N;
  int* bs = (int*)(ws + off); off += 256;
  int* bs2 = (int*)(ws + off); off += 256;
  u16* WqkvsT = (u16*)(ws + off); off += 32768;
  u16* W1T = (u16*)(ws + off); off += 32768;
  u16* W2T = (u16*)(ws + off); off += 32768;
  u16* WbdT = (u16*)(ws + off); off += 16384;
  float* msgE = q;        // q dead after fused_edge
  u16* tbf = (u16*)qwe;   // FFN intermediate aliases qwe

  hipMemsetAsync(cnt, 0, (size_t)N * sizeof(int), stream);
  convert_weights<<<896, 256, 0, stream>>>(Wq, Wk, Wv, Wskip, W1, W2, We,
                                           WqkvsT, W1T, W2T, WbdT);

  int ln_blocks = (N + 3) / 4;
  ln_kernel<<<ln_blocks, 256, 0, stream>>>(x, h_bf, ln1w, ln1b, N);

  dim3 gq((N + 127) / 128, 4);
  gemm_bf16<0><<<gq, 256, 0, stream>>>(h_bf, WqkvsT, N, 128, bq, bk, bv, bskip,
                                       q, pkv, nullptr, skipx1, nullptr);

  int nb = (N + 255) / 256;
  hist_kernel<<<1024, 256, 0, stream>>>(ei + E, cnt, E);
  scan_partial<<<nb, 256, 0, stream>>>(cnt, bs, N);
  scan_bs<<<1, 256, 0, stream>>>(bs, bs2, nb);
  scan_final<<<nb, 256, 0, stream>>>(cnt, bs2, offs, woff, N);
  scatter_kernel<<<1024, 256, 0, stream>>>(ei, woff, sorted, E);

  qwe_kernel<<<(N + 3) / 4, 256, 0, stream>>>(q, We, be, qwe, qbe, N);

  int fe_blocks = (N + 15) / 16;  // 4 waves/block, 4 nodes/wave
  fused_edge<<<fe_blocks, 256, 0, stream>>>(offs, cnt, sorted, ea, be, q, pkv,
                                            qwe, qbe, msg, weab, lbuf, N, E);

  // e-recombine as block-diagonal GEMM: msgE[N,128] = WEA[N,256] @ We_bd[256,128]
  dim3 ge((N + 127) / 128, 1);
  gemm_bf16<3><<<ge, 256, 0, stream>>>((const u16*)weab, WbdT, N, 256, nullptr,
                                       nullptr, nullptr, nullptr, msgE, nullptr,
                                       nullptr, nullptr, nullptr);

  finalize1_kernel<<<ln_blocks, 256, 0, stream>>>(x, msg, msgE, lbuf, be, skipx1,
                                                  ln2w, ln2b, h2bf, N);

  dim3 gf1((N + 127) / 128, 4);
  gemm_bf16<1><<<gf1, 256, 0, stream>>>(h2bf, W1T, N, 128, b1p, nullptr, nullptr,
                                        nullptr, nullptr, nullptr, tbf, nullptr, nullptr);
  dim3 gf2((N + 127) / 128, 1);
  gemm_bf16<2><<<gf2, 256, 0, stream>>>(tbf, W2T, N, 512, b2p, nullptr, nullptr,
                                        nullptr, (float*)d_out, nullptr, nullptr,
                                        nullptr, skipx1);
}

// Round 6
// 472.108 us; speedup vs baseline: 1.7002x; 1.0352x over previous
//
#include <hip/hip_runtime.h>
#include <math.h>

#define HID 128
#define EDGE_D 32
#define SC 0.36067376f  // 0.25 * log2(e)

typedef unsigned short u16;
typedef unsigned int u32;
typedef __bf16 bf16x8 __attribute__((ext_vector_type(8)));
typedef float f32x4 __attribute__((ext_vector_type(4)));
typedef u32 u32x4 __attribute__((ext_vector_type(4)));
typedef u32 u32x2 __attribute__((ext_vector_type(2)));

static __device__ __forceinline__ u16 f2bf(float f) {
  u32 u = __float_as_uint(f);
  u += 0x7fffu + ((u >> 16) & 1u);
  return (u16)(u >> 16);
}
static __device__ __forceinline__ u32 pack2(float a, float b) {
  return (u32)f2bf(a) | ((u32)f2bf(b) << 16);
}
static __device__ __forceinline__ float bflo(u32 w) { return __uint_as_float(w << 16); }
static __device__ __forceinline__ float bfhi(u32 w) { return __uint_as_float(w & 0xffff0000u); }
// all-lanes sum within each 16-lane row via DPP row rotates (pure VALU)
static __device__ __forceinline__ float grp16_sum(float x) {
  x += __int_as_float(__builtin_amdgcn_mov_dpp(__float_as_int(x), 0x128, 0xf, 0xf, true));
  x += __int_as_float(__builtin_amdgcn_mov_dpp(__float_as_int(x), 0x124, 0xf, 0xf, true));
  x += __int_as_float(__builtin_amdgcn_mov_dpp(__float_as_int(x), 0x122, 0xf, 0xf, true));
  x += __int_as_float(__builtin_amdgcn_mov_dpp(__float_as_int(x), 0x121, 0xf, 0xf, true));
  return x;
}
static __device__ __forceinline__ float wave_allreduce_sum(float v) {
#pragma unroll
  for (int off = 32; off > 0; off >>= 1) v += __shfl_xor(v, off);
  return v;
}

// ---------- LayerNorm: out_bf16 = LN(in) ----------
__global__ __launch_bounds__(256) void ln_kernel(const float* __restrict__ in,
                                                 u16* __restrict__ out,
                                                 const float* __restrict__ w,
                                                 const float* __restrict__ b, int n) {
  int row0 = blockIdx.x * 4 + (threadIdx.x >> 6);
  int lane = threadIdx.x & 63;
  int stride = gridDim.x * 4;
  for (int row = row0; row < n; row += stride) {
    const float* p = in + (size_t)row * HID;
    float a = p[lane], c = p[lane + 64];
    float s = wave_allreduce_sum(a + c);
    float s2 = wave_allreduce_sum(a * a + c * c);
    float mean = s * (1.f / 128.f);
    float var = s2 * (1.f / 128.f) - mean * mean;
    float rs = rsqrtf(var + 1e-5f);
    u16* o = out + (size_t)row * HID;
    o[lane] = f2bf((a - mean) * rs * w[lane] + b[lane]);
    o[lane + 64] = f2bf((c - mean) * rs * w[lane + 64] + b[lane + 64]);
  }
}

// ---------- finalize conv + LN2 ----------
// x1 = x + msg/l + be + skip (in-place over skip); h2_bf16 = LN(x1)
__global__ __launch_bounds__(256) void finalize1_kernel(
    const float* __restrict__ x, const float* __restrict__ msg,
    const float* __restrict__ lbuf, const float* __restrict__ be,
    float* __restrict__ skipx1, const float* __restrict__ w,
    const float* __restrict__ b, u16* __restrict__ h2, int n) {
  int row0 = blockIdx.x * 4 + (threadIdx.x >> 6);
  int lane = threadIdx.x & 63;
  int stride = gridDim.x * 4;
  float be0 = be[lane], be1 = be[lane + 64];
  for (int row = row0; row < n; row += stride) {
    size_t base = (size_t)row * HID;
    float inv0 = 1.f / (lbuf[(size_t)row * 8 + (lane >> 4)] + 1e-30f);
    float inv1 = 1.f / (lbuf[(size_t)row * 8 + 4 + (lane >> 4)] + 1e-30f);
    float a = x[base + lane] + msg[base + lane] * inv0 + be0 + skipx1[base + lane];
    float c = x[base + 64 + lane] + msg[base + 64 + lane] * inv1 + be1 +
              skipx1[base + 64 + lane];
    skipx1[base + lane] = a;
    skipx1[base + 64 + lane] = c;
    float s = wave_allreduce_sum(a + c);
    float s2 = wave_allreduce_sum(a * a + c * c);
    float mean = s * (1.f / 128.f);
    float var = s2 * (1.f / 128.f) - mean * mean;
    float rs = rsqrtf(var + 1e-5f);
    h2[base + lane] = f2bf((a - mean) * rs * w[lane] + b[lane]);
    h2[base + 64 + lane] = f2bf((c - mean) * rs * w[lane + 64] + b[lane + 64]);
  }
}

// ---------- weight conversion: f32 -> transposed bf16 [M][K]; + block-diag We^T ----------
__global__ __launch_bounds__(256) void convert_weights(
    const float* __restrict__ Wq, const float* __restrict__ Wk,
    const float* __restrict__ Wv, const float* __restrict__ Ws,
    const float* __restrict__ W1, const float* __restrict__ W2,
    const float* __restrict__ We, u16* __restrict__ WqkvsT,
    u16* __restrict__ W1T, u16* __restrict__ W2T, u16* __restrict__ WbdT) {
  int idx = blockIdx.x * 256 + threadIdx.x;
  if (idx < 65536) {
    int m = idx >> 7, k = idx & 127;
    const float* Wm = m < 128 ? Wq : m < 256 ? Wk : m < 384 ? Wv : Ws;
    WqkvsT[idx] = f2bf(Wm[k * 128 + (m & 127)]);
  } else if (idx < 131072) {
    int j = idx - 65536;
    int m = j >> 7, k = j & 127;
    W1T[j] = f2bf(W1[k * 512 + m]);
  } else if (idx < 196608) {
    int j = idx - 131072;
    int m = j >> 9, k = j & 511;
    W2T[j] = f2bf(W2[k * 128 + m]);
  } else if (idx < 229376) {
    int j = idx - 196608;  // WbdT [128][256]
    int m = j >> 8, c = j & 255;
    WbdT[j] = ((c >> 5) == (m >> 4)) ? f2bf(We[(c & 31) * 128 + m]) : (u16)0;
  }
}

// ---------- bf16 MFMA GEMM: tile 128x128, 4 waves, 2-phase double-buffered LDS ----------
// EPI: 0 = QKVS (y0->pq packed, y1/y2->pkv packed, y3->skip f32)
//      1 = GELU->bf16 ; 2 = +bias+add->f32 ; 4 = +addsrc->f32 (no bias)
#define GSTAGE(buf, kc)                                                        \
  {                                                                            \
    _Pragma("unroll") for (int i = 0; i < 2; i++) {                            \
      int idx = i * 256 + t;                                                   \
      int row = idx >> 2, c4 = idx & 3;                                        \
      __builtin_amdgcn_global_load_lds(                                        \
          (const __attribute__((address_space(1))) u32*)(A + (size_t)(r0 + row) * K + (kc) + c4 * 8), \
          (__attribute__((address_space(3))) u32*)&As[buf][idx * 8], 16, 0, 0);\
      __builtin_amdgcn_global_load_lds(                                        \
          (const __attribute__((address_space(1))) u32*)(Bt + (size_t)(c0 + row) * K + (kc) + c4 * 8), \
          (__attribute__((address_space(3))) u32*)&Bs[buf][idx * 8], 16, 0, 0);\
    }                                                                          \
  }

template <int EPI, int K>
__global__ __launch_bounds__(256) void gemm_bf16(
    const u16* __restrict__ A, const u16* __restrict__ Bt, int n,
    const float* __restrict__ bias0, const float* __restrict__ bias1,
    const float* __restrict__ bias2, const float* __restrict__ bias3,
    float* __restrict__ of0, u32* __restrict__ opq, u32* __restrict__ pkv,
    u16* __restrict__ ob1, const float* __restrict__ addsrc) {
  __shared__ u16 As[2][128 * 32];
  __shared__ u16 Bs[2][128 * 32];
  int t = threadIdx.x;
  int w = t >> 6, lane = t & 63;
  int g = lane >> 4, sr = lane & 15;
  int r0 = blockIdx.x * 128;
  int c0 = blockIdx.y * 128;
  f32x4 acc[2][8];
#pragma unroll
  for (int m = 0; m < 2; m++)
#pragma unroll
    for (int nn = 0; nn < 8; nn++) acc[m][nn] = {0.f, 0.f, 0.f, 0.f};

  constexpr int NT = K / 32;
  GSTAGE(0, 0)
  __syncthreads();
#pragma unroll
  for (int tt = 0; tt < NT; tt++) {
    if (tt + 1 < NT) GSTAGE((tt + 1) & 1, (tt + 1) * 32)
    bf16x8 a0 = *(const bf16x8*)&As[tt & 1][(w * 32 + sr) * 32 + g * 8];
    bf16x8 a1 = *(const bf16x8*)&As[tt & 1][(w * 32 + 16 + sr) * 32 + g * 8];
#pragma unroll
    for (int nn = 0; nn < 8; nn++) {
      bf16x8 b = *(const bf16x8*)&Bs[tt & 1][(nn * 16 + sr) * 32 + g * 8];
      acc[0][nn] = __builtin_amdgcn_mfma_f32_16x16x32_bf16(a0, b, acc[0][nn], 0, 0, 0);
      acc[1][nn] = __builtin_amdgcn_mfma_f32_16x16x32_bf16(a1, b, acc[1][nn], 0, 0, 0);
    }
    __syncthreads();
  }

  if (EPI == 0 && blockIdx.y == 0) {  // Q packed
#pragma unroll
    for (int m = 0; m < 2; m++)
#pragma unroll
      for (int nn = 0; nn < 4; nn++)
#pragma unroll
        for (int j = 0; j < 4; j++) {
          int row = r0 + w * 32 + m * 16 + g * 4 + j;
          if (row < n) {
            int cj = nn * 16 + sr;
            opq[((size_t)row << 6) + cj] =
                pack2(acc[m][nn][j] + bias0[cj], acc[m][nn + 4][j] + bias0[cj + 64]);
          }
        }
    return;
  }
  if (EPI == 0 && (blockIdx.y == 1 || blockIdx.y == 2)) {  // K/V packed
    const float* bp = blockIdx.y == 1 ? bias1 : bias2;
    int which = blockIdx.y - 1;
#pragma unroll
    for (int m = 0; m < 2; m++)
#pragma unroll
      for (int nn = 0; nn < 4; nn++)
#pragma unroll
        for (int j = 0; j < 4; j++) {
          int row = r0 + w * 32 + m * 16 + g * 4 + j;
          if (row < n) {
            int cj = nn * 16 + sr;
            pkv[((size_t)row << 7) + (cj << 1) + which] =
                pack2(acc[m][nn][j] + bp[cj], acc[m][nn + 4][j] + bp[cj + 64]);
          }
        }
    return;
  }
#pragma unroll
  for (int m = 0; m < 2; m++)
#pragma unroll
    for (int nn = 0; nn < 8; nn++)
#pragma unroll
      for (int j = 0; j < 4; j++) {
        int row = r0 + w * 32 + m * 16 + g * 4 + j;
        if (row < n) {
          int cj = nn * 16 + sr;
          float val = acc[m][nn][j];
          if (EPI == 0) {  // y==3: skip, f32
            of0[(size_t)row * HID + cj] = val + bias3[cj];
          } else if (EPI == 1) {
            int cjg = blockIdx.y * 128 + cj;
            float v2 = val + bias0[cjg];
            v2 = 0.5f * v2 * (1.f + erff(v2 * 0.70710678118f));
            ob1[(size_t)row * 512 + cjg] = f2bf(v2);
          } else if (EPI == 2) {
            of0[(size_t)row * HID + cj] = val + bias0[cj] + addsrc[(size_t)row * HID + cj];
          } else {  // EPI == 4
            of0[(size_t)row * HID + cj] = val + addsrc[(size_t)row * HID + cj];
          }
        }
      }
}

// ---------- counting sort by dst ----------
__global__ __launch_bounds__(256) void hist_kernel(const int* __restrict__ dstp,
                                                   int* __restrict__ cnt, int E) {
  int i = blockIdx.x * blockDim.x + threadIdx.x;
  int stride = gridDim.x * blockDim.x;
  for (; i < E; i += stride) atomicAdd(&cnt[dstp[i]], 1);
}

__global__ __launch_bounds__(256) void scan_partial(const int* __restrict__ cnt,
                                                    int* __restrict__ bs, int N) {
  __shared__ int sd[256];
  int idx = blockIdx.x * 256 + threadIdx.x;
  sd[threadIdx.x] = (idx < N) ? cnt[idx] : 0;
  __syncthreads();
  for (int s = 128; s > 0; s >>= 1) {
    if (threadIdx.x < s) sd[threadIdx.x] += sd[threadIdx.x + s];
    __syncthreads();
  }
  if (threadIdx.x == 0) bs[blockIdx.x] = sd[0];
}

__global__ __launch_bounds__(256) void scan_bs(const int* __restrict__ bs,
                                               int* __restrict__ bs2, int nb) {
  __shared__ int sd[256];
  int t = threadIdx.x;
  int v = (t < nb) ? bs[t] : 0;
  sd[t] = v;
  __syncthreads();
  for (int s = 1; s < 256; s <<= 1) {
    int add = (t >= s) ? sd[t - s] : 0;
    __syncthreads();
    sd[t] += add;
    __syncthreads();
  }
  bs2[t] = sd[t] - v;  // exclusive
}

__global__ __launch_bounds__(256) void scan_final(const int* __restrict__ cnt,
                                                  const int* __restrict__ bs2,
                                                  int* __restrict__ offs,
                                                  int* __restrict__ woff, int N) {
  __shared__ int sd[256];
  int t = threadIdx.x;
  int idx = blockIdx.x * 256 + t;
  int v = (idx < N) ? cnt[idx] : 0;
  sd[t] = v;
  __syncthreads();
  for (int s = 1; s < 256; s <<= 1) {
    int add = (t >= s) ? sd[t - s] : 0;
    __syncthreads();
    sd[t] += add;
    __syncthreads();
  }
  if (idx < N) {
    int ex = sd[t] - v + bs2[blockIdx.x];
    offs[idx] = ex;
    woff[idx] = ex;
  }
}

// scatter: also repack edge_attr to dst-sorted bf16 rows (64B/edge)
__global__ __launch_bounds__(256) void scatter_kernel(const int* __restrict__ ei,
                                                      const float* __restrict__ ea,
                                                      int* __restrict__ woff,
                                                      int* __restrict__ srcs,
                                                      u32* __restrict__ eab, int E) {
  int i = blockIdx.x * blockDim.x + threadIdx.x;
  int stride = gridDim.x * blockDim.x;
  for (; i < E; i += stride) {
    int src = ei[i];
    int dst = ei[E + i];
    int pos = atomicAdd(&woff[dst], 1);
    srcs[pos] = src;
    const float4* er = (const float4*)(ea + (size_t)i * 32);
    u32* ob = eab + ((size_t)pos << 4);
#pragma unroll
    for (int jq = 0; jq < 4; jq++) {
      float4 v0 = er[2 * jq], v1 = er[2 * jq + 1];
      u32x4 pkd = {pack2(v0.x, v0.y), pack2(v0.z, v0.w), pack2(v1.x, v1.y),
                   pack2(v1.z, v1.w)};
      *(u32x4*)(ob + jq * 4) = pkd;
    }
  }
}

// ---------- qWe precompute (reads packed q, writes packed bf16 qweb) ----------
__global__ __launch_bounds__(256) void qwe_kernel(const u32* __restrict__ pq,
                                                  const float* __restrict__ We,
                                                  const float* __restrict__ be,
                                                  u32* __restrict__ qweb,
                                                  float* __restrict__ qbe, int Nn) {
  __shared__ float sWe[32][129];
  __shared__ float sbe[128];
  int t = threadIdx.x;
  for (int i = t; i < 32 * 128; i += 256) sWe[i >> 7][i & 127] = We[i];
  if (t < 128) sbe[t] = be[t];
  __syncthreads();
  int lane = t & 63, w = t >> 6;
  int g = lane >> 4, sr = lane & 15;
  int node = blockIdx.x * 4 + w;
  if (node >= Nn) return;
  u32 pw = pq[(size_t)node * 64 + lane];
  float q0 = bflo(pw), q1 = bfhi(pw);
  float o00 = 0.f, o01 = 0.f, o10 = 0.f, o11 = 0.f;
  int base = lane & 48;
#pragma unroll
  for (int d0 = 0; d0 < 16; d0++) {
    float qa = __shfl(q0, base + d0);
    float qb = __shfl(q1, base + d0);
    int col = base + d0;
    o00 += qa * sWe[2 * sr][col];
    o01 += qa * sWe[2 * sr + 1][col];
    o10 += qb * sWe[2 * sr][64 + col];
    o11 += qb * sWe[2 * sr + 1][64 + col];
  }
  qweb[(size_t)node * 128 + g * 16 + sr] = pack2(o00 * SC, o01 * SC);
  qweb[(size_t)node * 128 + 64 + g * 16 + sr] = pack2(o10 * SC, o11 * SC);
  float t0 = grp16_sum(q0 * sbe[lane]);
  float t1 = grp16_sum(q1 * sbe[lane + 64]);
  if (sr == 0) {
    qbe[node * 8 + g] = t0 * SC;
    qbe[node * 8 + 4 + g] = t1 * SC;
  }
}

// ---------- fused edge attention ----------
#define ISSUE4(P, base_)                                                       \
  {                                                                            \
    _Pragma("unroll") for (int jj = 0; jj < 4; jj++) {                         \
      int sj = min(base_ + jj, segn - 1);                                      \
      int sxx = __builtin_amdgcn_readlane(seR, sj);                            \
      P##kv[jj] = *(const u32x2*)(pkv + ((size_t)sxx << 7) + (lane << 1));     \
      P##ea[jj] = eab[(((size_t)(ebase + sj)) << 4) + sr];                     \
    }                                                                          \
  }

#define COMP4(P, base_)                                                        \
  {                                                                            \
    _Pragma("unroll") for (int jj = 0; jj < 4; jj++) {                         \
      u32 kx = P##kv[jj].x, ky = P##kv[jj].y, ew = P##ea[jj];                  \
      float k0 = bflo(kx), k1 = bfhi(kx);                                      \
      float v0f = bflo(ky), v1f = bfhi(ky);                                    \
      float ex = bflo(ew), ey = bfhi(ew);                                      \
      float p0 = fmaf(q0C, k0, fmaf(qw0x, ex, qw0y * ey));                     \
      float p1 = fmaf(q1C, k1, fmaf(qw1x, ex, qw1y * ey));                     \
      p0 = grp16_sum(p0) + qb0C;                                               \
      p1 = grp16_sum(p1) + qb1C;                                               \
      bool val_ = (base_ + jj) < segn;                                         \
      float w1 = val_ ? __builtin_amdgcn_exp2f(p0) : 0.f;                      \
      float w2 = val_ ? __builtin_amdgcn_exp2f(p1) : 0.f;                      \
      l1 += w1;                                                                \
      l2 += w2;                                                                \
      a0 = fmaf(w1, v0f, a0);                                                  \
      a1 = fmaf(w2, v1f, a1);                                                  \
      wa00 = fmaf(w1, ex, wa00);                                               \
      wa01 = fmaf(w1, ey, wa01);                                               \
      wa10 = fmaf(w2, ex, wa10);                                               \
      wa11 = fmaf(w2, ey, wa11);                                               \
    }                                                                          \
  }

__global__ __launch_bounds__(256) void fused_edge(
    const int* __restrict__ offs, const int* __restrict__ cnt,
    const int* __restrict__ srcs, const u32* __restrict__ eab,
    const float* __restrict__ be, const u32* __restrict__ pq,
    const u32* __restrict__ pkv, const u32* __restrict__ qweb,
    const float* __restrict__ qbe, float* __restrict__ msg,
    u32* __restrict__ weab, float* __restrict__ lbuf, int Nn, int Etot) {
  int lane = threadIdx.x & 63;
  int w = threadIdx.x >> 6;
  int g = lane >> 4, sr = lane & 15;
  int wid = blockIdx.x * 4 + w;
  int nw = gridDim.x * 4;
  int per = (Nn + nw - 1) / nw;
  int n0 = wid * per;
  int n1 = min(Nn, n0 + per);
  if (n0 >= n1) return;
  int nn = n1 - n0;

  float be0 = be[lane], be1 = be[lane + 64];

  int ml = min(lane, nn - 1);
  int myBeg = offs[n0 + ml];
  int myCnt = cnt[n0 + ml];

  // prefetch node 0 state
  int beg = __builtin_amdgcn_readlane(myBeg, 0);
  int num = __builtin_amdgcn_readlane(myCnt, 0);
  int seC = srcs[min(beg + min(lane, max(num - 1, 0)), Etot - 1)];
  u32 pqC = pq[(size_t)n0 * 64 + lane];
  u32 qwb0C = qweb[(size_t)n0 * 128 + g * 16 + sr];
  u32 qwb1C = qweb[(size_t)n0 * 128 + 64 + g * 16 + sr];
  float qb0C = qbe[(size_t)n0 * 8 + g], qb1C = qbe[(size_t)n0 * 8 + 4 + g];

  for (int ni = 0; ni < nn; ni++) {
    int node = n0 + ni;
    // next-node prefetch (independent of current compute)
    int begX = 0, numX = 0, seX = 0;
    u32 pqX = 0, qwb0X = 0, qwb1X = 0;
    float qb0X = 0.f, qb1X = 0.f;
    if (ni + 1 < nn) {
      begX = __builtin_amdgcn_readlane(myBeg, ni + 1);
      numX = __builtin_amdgcn_readlane(myCnt, ni + 1);
      seX = srcs[min(begX + min(lane, max(numX - 1, 0)), Etot - 1)];
      pqX = pq[(size_t)(node + 1) * 64 + lane];
      qwb0X = qweb[(size_t)(node + 1) * 128 + g * 16 + sr];
      qwb1X = qweb[(size_t)(node + 1) * 128 + 64 + g * 16 + sr];
      qb0X = qbe[(size_t)(node + 1) * 8 + g];
      qb1X = qbe[(size_t)(node + 1) * 8 + 4 + g];
    }
    float q0C = bflo(pqC) * SC, q1C = bfhi(pqC) * SC;
    float qw0x = bflo(qwb0C), qw0y = bfhi(qwb0C);
    float qw1x = bflo(qwb1C), qw1y = bfhi(qwb1C);
    float l1 = 0.f, l2 = 0.f, a0 = 0.f, a1 = 0.f;
    float wa00 = 0.f, wa01 = 0.f, wa10 = 0.f, wa11 = 0.f;
    if (num > 0) {
      int cb = 0;
      int seR = seC;
      while (true) {
        int segn = min(num - cb, 64);
        int ebase = beg + cb;
        u32x2 Akv[4], Bkv[4];
        u32 Aea[4], Bea[4];
        ISSUE4(A, 0)
        for (int c = 0; c < segn; c += 8) {
          ISSUE4(B, c + 4)
          COMP4(A, c)
          ISSUE4(A, c + 8)
          COMP4(B, c + 4)
        }
        cb += 64;
        if (cb >= num) break;
        int rem = num - cb;
        seR = srcs[min(beg + cb + min(lane, rem - 1), Etot - 1)];
      }
    }
    size_t ob = (size_t)node * HID + lane;
    if (num > 0) {
      msg[ob] = a0;
      msg[ob + 64] = a1;
    } else {  // empty segment: finalize adds be -> cancel it
      msg[ob] = -be0;
      msg[ob + 64] = -be1;
    }
    weab[(size_t)node * 128 + g * 16 + sr] = pack2(wa00, wa01);
    weab[(size_t)node * 128 + 64 + g * 16 + sr] = pack2(wa10, wa11);
    if (sr == 0) {
      lbuf[(size_t)node * 8 + g] = (num > 0) ? l1 : 1.f;
      lbuf[(size_t)node * 8 + 4 + g] = (num > 0) ? l2 : 1.f;
    }
    beg = begX;
    num = numX;
    seC = seX;
    pqC = pqX;
    qwb0C = qwb0X;
    qwb1C = qwb1X;
    qb0C = qb0X;
    qb1C = qb1X;
  }
}

extern "C" void kernel_launch(void* const* d_in, const int* in_sizes, int n_in,
                              void* d_out, int out_size, void* d_ws, size_t ws_size,
                              hipStream_t stream) {
  const float* x = (const float*)d_in[0];
  const int* ei = (const int*)d_in[1];
  const float* ea = (const float*)d_in[2];
  const float* Wq = (const float*)d_in[3];
  const float* bq = (const float*)d_in[4];
  const float* Wk = (const float*)d_in[5];
  const float* bk = (const float*)d_in[6];
  const float* Wv = (const float*)d_in[7];
  const float* bv = (const float*)d_in[8];
  const float* We = (const float*)d_in[9];
  const float* be = (const float*)d_in[10];
  const float* Wskip = (const float*)d_in[11];
  const float* bskip = (const float*)d_in[12];
  const float* ln1w = (const float*)d_in[13];
  const float* ln1b = (const float*)d_in[14];
  const float* W1 = (const float*)d_in[15];
  const float* b1p = (const float*)d_in[16];
  const float* W2 = (const float*)d_in[17];
  const float* b2p = (const float*)d_in[18];
  const float* ln2w = (const float*)d_in[19];
  const float* ln2b = (const float*)d_in[20];

  int N = in_sizes[0] / HID;
  int E = in_sizes[1] / 2;
  size_t nf = (size_t)N * HID;

  float* ws = (float*)d_ws;
  size_t off = 0;
  u16* h_bf = (u16*)(ws + off); off += nf / 2;
  u32* pq = (u32*)(ws + off); off += nf / 2;   // [node][64] packed q
  u32* pkv = (u32*)(ws + off); off += nf;      // [node][64]{kword,vword}
  float* skipx1 = ws + off; off += nf;         // skip, overwritten with x1
  float* msg = ws + off; off += nf;
  u32* weab = (u32*)(ws + off); off += nf;     // [node][128] packed bf16 pairs
  float* lbuf = ws + off; off += (size_t)N * 8;
  u32* qweb = (u32*)(ws + off); off += nf;     // [node][128] packed bf16 qWe
  float* qbe = ws + off; off += (size_t)N * 8;
  int* srcs = (int*)(ws + off); off += E;
  u32* eab = (u32*)(ws + off); off += (size_t)E * 16;  // sorted bf16 edge_attr
  int* cnt = (int*)(ws + off); off += N;
  int* offs = (int*)(ws + off); off += N;
  int* woff = (int*)(ws + off); off += N;
  int* bs = (int*)(ws + off); off += 256;
  int* bs2 = (int*)(ws + off); off += 256;
  u16* WqkvsT = (u16*)(ws + off); off += 32768;
  u16* W1T = (u16*)(ws + off); off += 32768;
  u16* W2T = (u16*)(ws + off); off += 32768;
  u16* WbdT = (u16*)(ws + off); off += 16384;
  u16* h2bf = h_bf;        // h_bf dead after QKVS GEMM
  u16* tbf = (u16*)eab;    // FFN intermediate aliases eab (dead after fused_edge)

  hipMemsetAsync(cnt, 0, (size_t)N * sizeof(int), stream);
  convert_weights<<<896, 256, 0, stream>>>(Wq, Wk, Wv, Wskip, W1, W2, We,
                                           WqkvsT, W1T, W2T, WbdT);

  int ln_blocks = (N + 3) / 4;
  ln_kernel<<<ln_blocks, 256, 0, stream>>>(x, h_bf, ln1w, ln1b, N);

  dim3 gq((N + 127) / 128, 4);
  gemm_bf16<0, 128><<<gq, 256, 0, stream>>>(h_bf, WqkvsT, N, bq, bk, bv, bskip,
                                            skipx1, pq, pkv, nullptr, nullptr);

  int nb = (N + 255) / 256;
  hist_kernel<<<1024, 256, 0, stream>>>(ei + E, cnt, E);
  scan_partial<<<nb, 256, 0, stream>>>(cnt, bs, N);
  scan_bs<<<1, 256, 0, stream>>>(bs, bs2, nb);
  scan_final<<<nb, 256, 0, stream>>>(cnt, bs2, offs, woff, N);
  scatter_kernel<<<1024, 256, 0, stream>>>(ei, ea, woff, srcs, eab, E);

  qwe_kernel<<<(N + 3) / 4, 256, 0, stream>>>(pq, We, be, qweb, qbe, N);

  int fe_blocks = (N + 15) / 16;  // 4 waves/block, 4 nodes/wave
  fused_edge<<<fe_blocks, 256, 0, stream>>>(offs, cnt, srcs, eab, be, pq, pkv,
                                            qweb, qbe, msg, weab, lbuf, N, E);

  // e-recombine: msg += WEA[N,256] @ We_bd[256,128]
  dim3 ge((N + 127) / 128, 1);
  gemm_bf16<4, 256><<<ge, 256, 0, stream>>>((const u16*)weab, WbdT, N, nullptr,
                                            nullptr, nullptr, nullptr, msg, nullptr,
                                            nullptr, nullptr, msg);

  finalize1_kernel<<<ln_blocks, 256, 0, stream>>>(x, msg, lbuf, be, skipx1, ln2w,
                                                  ln2b, h2bf, N);

  dim3 gf1((N + 127) / 128, 4);
  gemm_bf16<1, 128><<<gf1, 256, 0, stream>>>(h2bf, W1T, N, b1p, nullptr, nullptr,
                                             nullptr, nullptr, nullptr, nullptr,
                                             tbf, nullptr);
  dim3 gf2((N + 127) / 128, 1);
  gemm_bf16<2, 512><<<gf2, 256, 0, stream>>>(tbf, W2T, N, b2p, nullptr, nullptr,
                                             nullptr, (float*)d_out, nullptr,
                                             nullptr, nullptr, skipx1);
}

// Round 8
// 460.470 us; speedup vs baseline: 1.7432x; 1.0253x over previous
//
#include <hip/hip_runtime.h>
#include <math.h>

#define HID 128
#define EDGE_D 32
#define SC 0.36067376f  // 0.25 * log2(e)

typedef unsigned short u16;
typedef unsigned int u32;
typedef __bf16 bf16x8 __attribute__((ext_vector_type(8)));
typedef float f32x4 __attribute__((ext_vector_type(4)));
typedef u32 u32x4 __attribute__((ext_vector_type(4)));
typedef u32 u32x2 __attribute__((ext_vector_type(2)));

static __device__ __forceinline__ u16 f2bf(float f) {
  u32 u = __float_as_uint(f);
  u += 0x7fffu + ((u >> 16) & 1u);
  return (u16)(u >> 16);
}
static __device__ __forceinline__ u32 pack2(float a, float b) {
  return (u32)f2bf(a) | ((u32)f2bf(b) << 16);
}
static __device__ __forceinline__ float bflo(u32 w) { return __uint_as_float(w << 16); }
static __device__ __forceinline__ float bfhi(u32 w) { return __uint_as_float(w & 0xffff0000u); }
// all-lanes sum within each 16-lane row via DPP row rotates (pure VALU)
static __device__ __forceinline__ float grp16_sum(float x) {
  x += __int_as_float(__builtin_amdgcn_mov_dpp(__float_as_int(x), 0x128, 0xf, 0xf, true));
  x += __int_as_float(__builtin_amdgcn_mov_dpp(__float_as_int(x), 0x124, 0xf, 0xf, true));
  x += __int_as_float(__builtin_amdgcn_mov_dpp(__float_as_int(x), 0x122, 0xf, 0xf, true));
  x += __int_as_float(__builtin_amdgcn_mov_dpp(__float_as_int(x), 0x121, 0xf, 0xf, true));
  return x;
}
static __device__ __forceinline__ float wave_allreduce_sum(float v) {
#pragma unroll
  for (int off = 32; off > 0; off >>= 1) v += __shfl_xor(v, off);
  return v;
}

// ---------- LayerNorm: out_bf16 = LN(in) ----------
__global__ __launch_bounds__(256) void ln_kernel(const float* __restrict__ in,
                                                 u16* __restrict__ out,
                                                 const float* __restrict__ w,
                                                 const float* __restrict__ b, int n) {
  int row0 = blockIdx.x * 4 + (threadIdx.x >> 6);
  int lane = threadIdx.x & 63;
  int stride = gridDim.x * 4;
  for (int row = row0; row < n; row += stride) {
    const float* p = in + (size_t)row * HID;
    float a = p[lane], c = p[lane + 64];
    float s = wave_allreduce_sum(a + c);
    float s2 = wave_allreduce_sum(a * a + c * c);
    float mean = s * (1.f / 128.f);
    float var = s2 * (1.f / 128.f) - mean * mean;
    float rs = rsqrtf(var + 1e-5f);
    u16* o = out + (size_t)row * HID;
    o[lane] = f2bf((a - mean) * rs * w[lane] + b[lane]);
    o[lane + 64] = f2bf((c - mean) * rs * w[lane + 64] + b[lane + 64]);
  }
}

// ---------- weight conversion: f32 -> transposed bf16 [M][K]; + block-diag We^T ----------
__global__ __launch_bounds__(256) void convert_weights(
    const float* __restrict__ Wq, const float* __restrict__ Wk,
    const float* __restrict__ Wv, const float* __restrict__ Ws,
    const float* __restrict__ W1, const float* __restrict__ W2,
    const float* __restrict__ We, u16* __restrict__ WqkvsT,
    u16* __restrict__ W1T, u16* __restrict__ W2T, u16* __restrict__ WbdT) {
  int idx = blockIdx.x * 256 + threadIdx.x;
  if (idx < 65536) {
    int m = idx >> 7, k = idx & 127;
    const float* Wm = m < 128 ? Wq : m < 256 ? Wk : m < 384 ? Wv : Ws;
    WqkvsT[idx] = f2bf(Wm[k * 128 + (m & 127)]);
  } else if (idx < 131072) {
    int j = idx - 65536;
    int m = j >> 7, k = j & 127;
    W1T[j] = f2bf(W1[k * 512 + m]);
  } else if (idx < 196608) {
    int j = idx - 131072;
    int m = j >> 9, k = j & 511;
    W2T[j] = f2bf(W2[k * 128 + m]);
  } else if (idx < 229376) {
    int j = idx - 196608;  // WbdT [128][256]
    int m = j >> 8, c = j & 255;
    WbdT[j] = ((c >> 5) == (m >> 4)) ? f2bf(We[(c & 31) * 128 + m]) : (u16)0;
  }
}

// ---------- bf16 MFMA GEMM: tile 128x128, 4 waves, 2-phase double-buffered LDS ----------
#define GSTAGE(buf, kc)                                                        \
  {                                                                            \
    _Pragma("unroll") for (int i = 0; i < 2; i++) {                            \
      int idx = i * 256 + t;                                                   \
      int row = idx >> 2, c4 = idx & 3;                                        \
      __builtin_amdgcn_global_load_lds(                                        \
          (const __attribute__((address_space(1))) u32*)(A + (size_t)(r0 + row) * K + (kc) + c4 * 8), \
          (__attribute__((address_space(3))) u32*)&As[buf][idx * 8], 16, 0, 0);\
      __builtin_amdgcn_global_load_lds(                                        \
          (const __attribute__((address_space(1))) u32*)(Bt + (size_t)(c0 + row) * K + (kc) + c4 * 8), \
          (__attribute__((address_space(3))) u32*)&Bs[buf][idx * 8], 16, 0, 0);\
    }                                                                          \
  }

#define GEMM_CORE                                                              \
  constexpr int NT = K / 32;                                                   \
  GSTAGE(0, 0)                                                                 \
  __syncthreads();                                                             \
  _Pragma("unroll") for (int tt = 0; tt < NT; tt++) {                          \
    if (tt + 1 < NT) GSTAGE((tt + 1) & 1, (tt + 1) * 32)                       \
    bf16x8 a0 = *(const bf16x8*)&As[tt & 1][(w * 32 + sr) * 32 + g * 8];       \
    bf16x8 a1 = *(const bf16x8*)&As[tt & 1][(w * 32 + 16 + sr) * 32 + g * 8];  \
    _Pragma("unroll") for (int nn = 0; nn < 8; nn++) {                         \
      bf16x8 b = *(const bf16x8*)&Bs[tt & 1][(nn * 16 + sr) * 32 + g * 8];     \
      acc[0][nn] = __builtin_amdgcn_mfma_f32_16x16x32_bf16(a0, b, acc[0][nn], 0, 0, 0); \
      acc[1][nn] = __builtin_amdgcn_mfma_f32_16x16x32_bf16(a1, b, acc[1][nn], 0, 0, 0); \
    }                                                                          \
    __syncthreads();                                                           \
  }

// EPI: 0 = QKVS (y0->pq packed, y1/y2->pkv packed, y3->skip f32)
//      1 = GELU->bf16 ; 2 = +bias+addsrc->f32
template <int EPI, int K>
__global__ __launch_bounds__(256) void gemm_bf16(
    const u16* __restrict__ A, const u16* __restrict__ Bt, int n,
    const float* __restrict__ bias0, const float* __restrict__ bias1,
    const float* __restrict__ bias2, const float* __restrict__ bias3,
    float* __restrict__ of0, u32* __restrict__ opq, u32* __restrict__ pkv,
    u16* __restrict__ ob1, const float* __restrict__ addsrc) {
  __shared__ u16 As[2][128 * 32];
  __shared__ u16 Bs[2][128 * 32];
  int t = threadIdx.x;
  int w = t >> 6, lane = t & 63;
  int g = lane >> 4, sr = lane & 15;
  int r0 = blockIdx.x * 128;
  int c0 = blockIdx.y * 128;
  f32x4 acc[2][8];
#pragma unroll
  for (int m = 0; m < 2; m++)
#pragma unroll
    for (int nn = 0; nn < 8; nn++) acc[m][nn] = {0.f, 0.f, 0.f, 0.f};

  GEMM_CORE

  if (EPI == 0 && blockIdx.y == 0) {  // Q packed
#pragma unroll
    for (int m = 0; m < 2; m++)
#pragma unroll
      for (int nn = 0; nn < 4; nn++)
#pragma unroll
        for (int j = 0; j < 4; j++) {
          int row = r0 + w * 32 + m * 16 + g * 4 + j;
          if (row < n) {
            int cj = nn * 16 + sr;
            opq[((size_t)row << 6) + cj] =
                pack2(acc[m][nn][j] + bias0[cj], acc[m][nn + 4][j] + bias0[cj + 64]);
          }
        }
    return;
  }
  if (EPI == 0 && (blockIdx.y == 1 || blockIdx.y == 2)) {  // K/V packed
    const float* bp = blockIdx.y == 1 ? bias1 : bias2;
    int which = blockIdx.y - 1;
#pragma unroll
    for (int m = 0; m < 2; m++)
#pragma unroll
      for (int nn = 0; nn < 4; nn++)
#pragma unroll
        for (int j = 0; j < 4; j++) {
          int row = r0 + w * 32 + m * 16 + g * 4 + j;
          if (row < n) {
            int cj = nn * 16 + sr;
            pkv[((size_t)row << 7) + (cj << 1) + which] =
                pack2(acc[m][nn][j] + bp[cj], acc[m][nn + 4][j] + bp[cj + 64]);
          }
        }
    return;
  }
#pragma unroll
  for (int m = 0; m < 2; m++)
#pragma unroll
    for (int nn = 0; nn < 8; nn++)
#pragma unroll
      for (int j = 0; j < 4; j++) {
        int row = r0 + w * 32 + m * 16 + g * 4 + j;
        if (row < n) {
          int cj = nn * 16 + sr;
          float val = acc[m][nn][j];
          if (EPI == 0) {  // y==3: skip, f32
            of0[(size_t)row * HID + cj] = val + bias3[cj];
          } else if (EPI == 1) {
            int cjg = blockIdx.y * 128 + cj;
            float v2 = val + bias0[cjg];
            v2 = 0.5f * v2 * (1.f + erff(v2 * 0.70710678118f));
            ob1[(size_t)row * 512 + cjg] = f2bf(v2);
          } else {  // EPI == 2
            of0[(size_t)row * HID + cj] = val + bias0[cj] + addsrc[(size_t)row * HID + cj];
          }
        }
      }
}

// ---------- bd-GEMM (K=256) fused with finalize + LN2 ----------
// msgE = WEA @ We_bd ; x1 = x + (msg+msgE)*linv + be + skip (in-place over skip);
// h2 = LN(x1) with ln2. Tile holds complete rows; each row sits in one 16-lane group.
__global__ __launch_bounds__(256) void gemm_bd_fin(
    const u16* __restrict__ A, const u16* __restrict__ Bt, int n,
    const float* __restrict__ x, const float* __restrict__ msg,
    const float* __restrict__ lbuf, const float* __restrict__ be,
    const float* __restrict__ lnw, const float* __restrict__ lnb,
    float* __restrict__ skipx1, u16* __restrict__ h2) {
  __shared__ u16 As[2][128 * 32];
  __shared__ u16 Bs[2][128 * 32];
  constexpr int K = 256;
  int t = threadIdx.x;
  int w = t >> 6, lane = t & 63;
  int g = lane >> 4, sr = lane & 15;
  int r0 = blockIdx.x * 128;
  int c0 = 0;
  f32x4 acc[2][8];
#pragma unroll
  for (int m = 0; m < 2; m++)
#pragma unroll
    for (int nn = 0; nn < 8; nn++) acc[m][nn] = {0.f, 0.f, 0.f, 0.f};

  GEMM_CORE

  float becol[8], wcol[8], bcol[8];
#pragma unroll
  for (int nn = 0; nn < 8; nn++) {
    int c = nn * 16 + sr;
    becol[nn] = be[c];
    wcol[nn] = lnw[c];
    bcol[nn] = lnb[c];
  }
#pragma unroll
  for (int m = 0; m < 2; m++)
#pragma unroll
    for (int j = 0; j < 4; j++) {
      int row = r0 + w * 32 + m * 16 + g * 4 + j;
      if (row < n) {
        const float* xr = x + (size_t)row * HID;
        const float* mr = msg + (size_t)row * HID;
        float* sxr = skipx1 + (size_t)row * HID;
        f32x4 L0 = *(const f32x4*)(lbuf + (size_t)row * 8);
        f32x4 L1 = *(const f32x4*)(lbuf + (size_t)row * 8 + 4);
        float tv[8];
        float s = 0.f, s2 = 0.f;
#pragma unroll
        for (int nn = 0; nn < 8; nn++) {
          int c = nn * 16 + sr;
          float linv = nn < 4 ? L0[nn] : L1[nn - 4];
          float t1 = xr[c] + (mr[c] + acc[m][nn][j]) * linv + becol[nn] + sxr[c];
          tv[nn] = t1;
          s += t1;
          s2 = fmaf(t1, t1, s2);
        }
        s = grp16_sum(s);
        s2 = grp16_sum(s2);
        float mean = s * (1.f / 128.f);
        float var = s2 * (1.f / 128.f) - mean * mean;
        float rs = rsqrtf(var + 1e-5f);
        u16* h2r = h2 + (size_t)row * HID;
#pragma unroll
        for (int nn = 0; nn < 8; nn++) {
          int c = nn * 16 + sr;
          sxr[c] = tv[nn];
          h2r[c] = f2bf((tv[nn] - mean) * rs * wcol[nn] + bcol[nn]);
        }
      }
    }
}

// ---------- counting sort by dst ----------
__global__ __launch_bounds__(256) void hist_kernel(const int* __restrict__ dstp,
                                                   int* __restrict__ cnt, int E) {
  int i = blockIdx.x * blockDim.x + threadIdx.x;
  int stride = gridDim.x * blockDim.x;
  for (; i < E; i += stride) atomicAdd(&cnt[dstp[i]], 1);
}

__global__ __launch_bounds__(256) void scan_partial(const int* __restrict__ cnt,
                                                    int* __restrict__ bs, int N) {
  __shared__ int sd[256];
  int idx = blockIdx.x * 256 + threadIdx.x;
  sd[threadIdx.x] = (idx < N) ? cnt[idx] : 0;
  __syncthreads();
  for (int s = 128; s > 0; s >>= 1) {
    if (threadIdx.x < s) sd[threadIdx.x] += sd[threadIdx.x + s];
    __syncthreads();
  }
  if (threadIdx.x == 0) bs[blockIdx.x] = sd[0];
}

__global__ __launch_bounds__(256) void scan_bs(const int* __restrict__ bs,
                                               int* __restrict__ bs2, int nb) {
  __shared__ int sd[256];
  int t = threadIdx.x;
  int v = (t < nb) ? bs[t] : 0;
  sd[t] = v;
  __syncthreads();
  for (int s = 1; s < 256; s <<= 1) {
    int add = (t >= s) ? sd[t - s] : 0;
    __syncthreads();
    sd[t] += add;
    __syncthreads();
  }
  bs2[t] = sd[t] - v;  // exclusive
}

__global__ __launch_bounds__(256) void scan_final(const int* __restrict__ cnt,
                                                  const int* __restrict__ bs2,
                                                  int* __restrict__ offs,
                                                  int* __restrict__ woff, int N) {
  __shared__ int sd[256];
  int t = threadIdx.x;
  int idx = blockIdx.x * 256 + t;
  int v = (idx < N) ? cnt[idx] : 0;
  sd[t] = v;
  __syncthreads();
  for (int s = 1; s < 256; s <<= 1) {
    int add = (t >= s) ? sd[t - s] : 0;
    __syncthreads();
    sd[t] += add;
    __syncthreads();
  }
  if (idx < N) {
    int ex = sd[t] - v + bs2[blockIdx.x];
    offs[idx] = ex;
    woff[idx] = ex;
  }
}

__global__ __launch_bounds__(256) void scatter_kernel(const int* __restrict__ ei,
                                                      int* __restrict__ woff,
                                                      int2* __restrict__ sorted,
                                                      int E) {
  int i = blockIdx.x * blockDim.x + threadIdx.x;
  int stride = gridDim.x * blockDim.x;
  for (; i < E; i += stride) {
    int src = ei[i];
    int dst = ei[E + i];
    int pos = atomicAdd(&woff[dst], 1);
    sorted[pos] = make_int2(src, i);
  }
}

// repack edge_attr into dst-sorted bf16 rows: sequential writes, random full-line reads.
// 8 lanes per edge; lane sub handles float4 #sub of the 32-float row.
__global__ __launch_bounds__(256) void repack_kernel(const int2* __restrict__ sorted,
                                                     const float* __restrict__ ea,
                                                     u32* __restrict__ eab, int E) {
  int tid = blockIdx.x * 256 + threadIdx.x;
  int e = tid >> 3, sub = tid & 7;
  if (e >= E) return;
  int eid = sorted[e].y;
  float4 v = ((const float4*)(ea + (size_t)eid * 32))[sub];
  u32x2 pk = {pack2(v.x, v.y), pack2(v.z, v.w)};
  *((u32x2*)(eab + ((size_t)e << 4)) + sub) = pk;
}

// ---------- qWe precompute (grid-stride; LDS staged once per block) ----------
__global__ __launch_bounds__(256) void qwe_kernel(const u32* __restrict__ pq,
                                                  const float* __restrict__ We,
                                                  const float* __restrict__ be,
                                                  u32* __restrict__ qweb,
                                                  float* __restrict__ qbe, int Nn) {
  __shared__ float sWe[32][129];
  __shared__ float sbe[128];
  int t = threadIdx.x;
  for (int i = t; i < 32 * 128; i += 256) sWe[i >> 7][i & 127] = We[i];
  if (t < 128) sbe[t] = be[t];
  __syncthreads();
  int lane = t & 63, w = t >> 6;
  int g = lane >> 4, sr = lane & 15;
  int base = lane & 48;
  int stride = gridDim.x * 4;
  for (int node = blockIdx.x * 4 + w; node < Nn; node += stride) {
    u32 pw = pq[(size_t)node * 64 + lane];
    float q0 = bflo(pw), q1 = bfhi(pw);
    float o00 = 0.f, o01 = 0.f, o10 = 0.f, o11 = 0.f;
#pragma unroll
    for (int d0 = 0; d0 < 16; d0++) {
      float qa = __shfl(q0, base + d0);
      float qb = __shfl(q1, base + d0);
      int col = base + d0;
      o00 += qa * sWe[2 * sr][col];
      o01 += qa * sWe[2 * sr + 1][col];
      o10 += qb * sWe[2 * sr][64 + col];
      o11 += qb * sWe[2 * sr + 1][64 + col];
    }
    qweb[(size_t)node * 128 + g * 16 + sr] = pack2(o00 * SC, o01 * SC);
    qweb[(size_t)node * 128 + 64 + g * 16 + sr] = pack2(o10 * SC, o11 * SC);
    float t0 = grp16_sum(q0 * sbe[lane]);
    float t1 = grp16_sum(q1 * sbe[lane + 64]);
    if (sr == 0) {
      qbe[node * 8 + g] = t0 * SC;
      qbe[node * 8 + 4 + g] = t1 * SC;
    }
  }
}

// ---------- fused edge attention ----------
#define ISSUE4(P, base_)                                                       \
  {                                                                            \
    _Pragma("unroll") for (int jj = 0; jj < 4; jj++) {                         \
      int sj = min(base_ + jj, segn - 1);                                      \
      int sxx = __builtin_amdgcn_readlane(seR, sj);                            \
      P##kv[jj] = *(const u32x2*)(pkv + ((size_t)sxx << 7) + (lane << 1));     \
      P##ea[jj] = eab[(((size_t)(ebase + sj)) << 4) + sr];                     \
    }                                                                          \
  }

#define COMP4(P, base_)                                                        \
  {                                                                            \
    _Pragma("unroll") for (int jj = 0; jj < 4; jj++) {                         \
      u32 kx = P##kv[jj].x, ky = P##kv[jj].y, ew = P##ea[jj];                  \
      float k0 = bflo(kx), k1 = bfhi(kx);                                      \
      float v0f = bflo(ky), v1f = bfhi(ky);                                    \
      float ex = bflo(ew), ey = bfhi(ew);                                      \
      float p0 = fmaf(q0C, k0, fmaf(qw0x, ex, qw0y * ey));                     \
      float p1 = fmaf(q1C, k1, fmaf(qw1x, ex, qw1y * ey));                     \
      p0 = grp16_sum(p0) + qb0C;                                               \
      p1 = grp16_sum(p1) + qb1C;                                               \
      bool val_ = (base_ + jj) < segn;                                         \
      float w1 = val_ ? __builtin_amdgcn_exp2f(p0) : 0.f;                      \
      float w2 = val_ ? __builtin_amdgcn_exp2f(p1) : 0.f;                      \
      l1 += w1;                                                                \
      l2 += w2;                                                                \
      a0 = fmaf(w1, v0f, a0);                                                  \
      a1 = fmaf(w2, v1f, a1);                                                  \
      wa00 = fmaf(w1, ex, wa00);                                               \
      wa01 = fmaf(w1, ey, wa01);                                               \
      wa10 = fmaf(w2, ex, wa10);                                               \
      wa11 = fmaf(w2, ey, wa11);                                               \
    }                                                                          \
  }

__global__ __launch_bounds__(256) void fused_edge(
    const int* __restrict__ offs, const int* __restrict__ cnt,
    const int2* __restrict__ sorted, const u32* __restrict__ eab,
    const float* __restrict__ be, const u32* __restrict__ pq,
    const u32* __restrict__ pkv, const u32* __restrict__ qweb,
    const float* __restrict__ qbe, float* __restrict__ msg,
    u32* __restrict__ weab, float* __restrict__ lbuf, int Nn, int Etot) {
  int lane = threadIdx.x & 63;
  int w = threadIdx.x >> 6;
  int g = lane >> 4, sr = lane & 15;
  int wid = blockIdx.x * 4 + w;
  int nw = gridDim.x * 4;
  int per = (Nn + nw - 1) / nw;
  int n0 = wid * per;
  int n1 = min(Nn, n0 + per);
  if (n0 >= n1) return;
  int nn = n1 - n0;

  float be0 = be[lane], be1 = be[lane + 64];

  int ml = min(lane, nn - 1);
  int myBeg = offs[n0 + ml];
  int myCnt = cnt[n0 + ml];

  // prefetch node 0 state
  int beg = __builtin_amdgcn_readlane(myBeg, 0);
  int num = __builtin_amdgcn_readlane(myCnt, 0);
  int seC = sorted[min(beg + min(lane, max(num - 1, 0)), Etot - 1)].x;
  u32 pqC = pq[(size_t)n0 * 64 + lane];
  u32 qwb0C = qweb[(size_t)n0 * 128 + g * 16 + sr];
  u32 qwb1C = qweb[(size_t)n0 * 128 + 64 + g * 16 + sr];
  float qb0C = qbe[(size_t)n0 * 8 + g], qb1C = qbe[(size_t)n0 * 8 + 4 + g];

  for (int ni = 0; ni < nn; ni++) {
    int node = n0 + ni;
    // next-node prefetch (independent of current compute)
    int begX = 0, numX = 0, seX = 0;
    u32 pqX = 0, qwb0X = 0, qwb1X = 0;
    float qb0X = 0.f, qb1X = 0.f;
    if (ni + 1 < nn) {
      begX = __builtin_amdgcn_readlane(myBeg, ni + 1);
      numX = __builtin_amdgcn_readlane(myCnt, ni + 1);
      seX = sorted[min(begX + min(lane, max(numX - 1, 0)), Etot - 1)].x;
      pqX = pq[(size_t)(node + 1) * 64 + lane];
      qwb0X = qweb[(size_t)(node + 1) * 128 + g * 16 + sr];
      qwb1X = qweb[(size_t)(node + 1) * 128 + 64 + g * 16 + sr];
      qb0X = qbe[(size_t)(node + 1) * 8 + g];
      qb1X = qbe[(size_t)(node + 1) * 8 + 4 + g];
    }
    float q0C = bflo(pqC) * SC, q1C = bfhi(pqC) * SC;
    float qw0x = bflo(qwb0C), qw0y = bfhi(qwb0C);
    float qw1x = bflo(qwb1C), qw1y = bfhi(qwb1C);
    float l1 = 0.f, l2 = 0.f, a0 = 0.f, a1 = 0.f;
    float wa00 = 0.f, wa01 = 0.f, wa10 = 0.f, wa11 = 0.f;
    if (num > 0) {
      int cb = 0;
      int seR = seC;
      while (true) {
        int segn = min(num - cb, 64);
        int ebase = beg + cb;
        u32x2 Akv[4], Bkv[4];
        u32 Aea[4], Bea[4];
        ISSUE4(A, 0)
        for (int c = 0; c < segn; c += 8) {
          ISSUE4(B, c + 4)
          COMP4(A, c)
          ISSUE4(A, c + 8)
          COMP4(B, c + 4)
        }
        cb += 64;
        if (cb >= num) break;
        int rem = num - cb;
        seR = sorted[min(beg + cb + min(lane, rem - 1), Etot - 1)].x;
      }
    }
    size_t ob = (size_t)node * HID + lane;
    if (num > 0) {
      msg[ob] = a0;
      msg[ob + 64] = a1;
    } else {  // empty segment: bd_fin adds be -> cancel it
      msg[ob] = -be0;
      msg[ob + 64] = -be1;
    }
    weab[(size_t)node * 128 + g * 16 + sr] = pack2(wa00, wa01);
    weab[(size_t)node * 128 + 64 + g * 16 + sr] = pack2(wa10, wa11);
    if (sr == 0) {  // store reciprocals (bd_fin multiplies)
      lbuf[(size_t)node * 8 + g] = (num > 0) ? 1.f / (l1 + 1e-30f) : 1.f;
      lbuf[(size_t)node * 8 + 4 + g] = (num > 0) ? 1.f / (l2 + 1e-30f) : 1.f;
    }
    beg = begX;
    num = numX;
    seC = seX;
    pqC = pqX;
    qwb0C = qwb0X;
    qwb1C = qwb1X;
    qb0C = qb0X;
    qb1C = qb1X;
  }
}

extern "C" void kernel_launch(void* const* d_in, const int* in_sizes, int n_in,
                              void* d_out, int out_size, void* d_ws, size_t ws_size,
                              hipStream_t stream) {
  const float* x = (const float*)d_in[0];
  const int* ei = (const int*)d_in[1];
  const float* ea = (const float*)d_in[2];
  const float* Wq = (const float*)d_in[3];
  const float* bq = (const float*)d_in[4];
  const float* Wk = (const float*)d_in[5];
  const float* bk = (const float*)d_in[6];
  const float* Wv = (const float*)d_in[7];
  const float* bv = (const float*)d_in[8];
  const float* We = (const float*)d_in[9];
  const float* be = (const float*)d_in[10];
  const float* Wskip = (const float*)d_in[11];
  const float* bskip = (const float*)d_in[12];
  const float* ln1w = (const float*)d_in[13];
  const float* ln1b = (const float*)d_in[14];
  const float* W1 = (const float*)d_in[15];
  const float* b1p = (const float*)d_in[16];
  const float* W2 = (const float*)d_in[17];
  const float* b2p = (const float*)d_in[18];
  const float* ln2w = (const float*)d_in[19];
  const float* ln2b = (const float*)d_in[20];

  int N = in_sizes[0] / HID;
  int E = in_sizes[1] / 2;
  size_t nf = (size_t)N * HID;

  float* ws = (float*)d_ws;
  size_t off = 0;
  u16* h_bf = (u16*)(ws + off); off += nf / 2;
  u32* pq = (u32*)(ws + off); off += nf / 2;   // [node][64] packed q
  u32* pkv = (u32*)(ws + off); off += nf;      // [node][64]{kword,vword}
  float* skipx1 = ws + off; off += nf;         // skip, overwritten with x1
  float* msg = ws + off; off += nf;
  u32* weab = (u32*)(ws + off); off += nf;     // [node][128] packed bf16 pairs
  float* lbuf = ws + off; off += (size_t)N * 8;  // reciprocals
  u32* qweb = (u32*)(ws + off); off += nf;     // [node][128] packed bf16 qWe
  float* qbe = ws + off; off += (size_t)N * 8;
  int2* sorted = (int2*)(ws + off); off += (size_t)E * 2;  // {src, eid}
  u32* eab = (u32*)(ws + off); off += (size_t)E * 16;      // sorted bf16 edge_attr
  int* cnt = (int*)(ws + off); off += N;
  int* offs = (int*)(ws + off); off += N;
  int* woff = (int*)(ws + off); off += N;
  int* bs = (int*)(ws + off); off += 256;
  int* bs2 = (int*)(ws + off); off += 256;
  u16* WqkvsT = (u16*)(ws + off); off += 32768;
  u16* W1T = (u16*)(ws + off); off += 32768;
  u16* W2T = (u16*)(ws + off); off += 32768;
  u16* WbdT = (u16*)(ws + off); off += 16384;
  u16* h2bf = h_bf;        // h_bf dead after QKVS GEMM
  u16* tbf = (u16*)eab;    // FFN intermediate aliases eab (dead after fused_edge)

  hipMemsetAsync(cnt, 0, (size_t)N * sizeof(int), stream);
  convert_weights<<<896, 256, 0, stream>>>(Wq, Wk, Wv, Wskip, W1, W2, We,
                                           WqkvsT, W1T, W2T, WbdT);

  int ln_blocks = (N + 3) / 4;
  ln_kernel<<<ln_blocks, 256, 0, stream>>>(x, h_bf, ln1w, ln1b, N);

  dim3 gq((N + 127) / 128, 4);
  gemm_bf16<0, 128><<<gq, 256, 0, stream>>>(h_bf, WqkvsT, N, bq, bk, bv, bskip,
                                            skipx1, pq, pkv, nullptr, nullptr);

  int nb = (N + 255) / 256;
  hist_kernel<<<1024, 256, 0, stream>>>(ei + E, cnt, E);
  scan_partial<<<nb, 256, 0, stream>>>(cnt, bs, N);
  scan_bs<<<1, 256, 0, stream>>>(bs, bs2, nb);
  scan_final<<<nb, 256, 0, stream>>>(cnt, bs2, offs, woff, N);
  scatter_kernel<<<1024, 256, 0, stream>>>(ei, woff, sorted, E);
  repack_kernel<<<(E * 8 + 255) / 256, 256, 0, stream>>>(sorted, ea, eab, E);

  qwe_kernel<<<1024, 256, 0, stream>>>(pq, We, be, qweb, qbe, N);

  int fe_blocks = (N + 15) / 16;  // 4 waves/block, 4 nodes/wave
  fused_edge<<<fe_blocks, 256, 0, stream>>>(offs, cnt, sorted, eab, be, pq, pkv,
                                            qweb, qbe, msg, weab, lbuf, N, E);

  // bd-GEMM + finalize + LN2 fused
  dim3 ge((N + 127) / 128, 1);
  gemm_bd_fin<<<ge, 256, 0, stream>>>((const u16*)weab, WbdT, N, x, msg, lbuf,
                                      be, ln2w, ln2b, skipx1, h2bf);

  dim3 gf1((N + 127) / 128, 4);
  gemm_bf16<1, 128><<<gf1, 256, 0, stream>>>(h2bf, W1T, N, b1p, nullptr, nullptr,
                                             nullptr, nullptr, nullptr, nullptr,
                                             tbf, nullptr);
  dim3 gf2((N + 127) / 128, 1);
  gemm_bf16<2, 512><<<gf2, 256, 0, stream>>>(tbf, W2T, N, b2p, nullptr, nullptr,
                                             nullptr, (float*)d_out, nullptr,
                                             nullptr, nullptr, skipx1);
}

// Round 9
// 438.254 us; speedup vs baseline: 1.8316x; 1.0507x over previous
//
#include <hip/hip_runtime.h>
#include <math.h>

#define HID 128
#define EDGE_D 32
#define SC 0.36067376f  // 0.25 * log2(e)

typedef unsigned short u16;
typedef unsigned int u32;
typedef __bf16 bf16x8 __attribute__((ext_vector_type(8)));
typedef float f32x4 __attribute__((ext_vector_type(4)));
typedef u32 u32x4 __attribute__((ext_vector_type(4)));
typedef u32 u32x2 __attribute__((ext_vector_type(2)));

static __device__ __forceinline__ u16 f2bf(float f) {
  u32 u = __float_as_uint(f);
  u += 0x7fffu + ((u >> 16) & 1u);
  return (u16)(u >> 16);
}
static __device__ __forceinline__ u32 pack2(float a, float b) {
  return (u32)f2bf(a) | ((u32)f2bf(b) << 16);
}
static __device__ __forceinline__ float bflo(u32 w) { return __uint_as_float(w << 16); }
static __device__ __forceinline__ float bfhi(u32 w) { return __uint_as_float(w & 0xffff0000u); }
// all-lanes sum within each 16-lane row via DPP row rotates (pure VALU)
static __device__ __forceinline__ float grp16_sum(float x) {
  x += __int_as_float(__builtin_amdgcn_mov_dpp(__float_as_int(x), 0x128, 0xf, 0xf, true));
  x += __int_as_float(__builtin_amdgcn_mov_dpp(__float_as_int(x), 0x124, 0xf, 0xf, true));
  x += __int_as_float(__builtin_amdgcn_mov_dpp(__float_as_int(x), 0x122, 0xf, 0xf, true));
  x += __int_as_float(__builtin_amdgcn_mov_dpp(__float_as_int(x), 0x121, 0xf, 0xf, true));
  return x;
}
static __device__ __forceinline__ float wave_allreduce_sum(float v) {
#pragma unroll
  for (int off = 32; off > 0; off >>= 1) v += __shfl_xor(v, off);
  return v;
}

// ---------- LayerNorm: out_bf16 = LN(in) ----------
__global__ __launch_bounds__(256) void ln_kernel(const float* __restrict__ in,
                                                 u16* __restrict__ out,
                                                 const float* __restrict__ w,
                                                 const float* __restrict__ b, int n) {
  int row0 = blockIdx.x * 4 + (threadIdx.x >> 6);
  int lane = threadIdx.x & 63;
  int stride = gridDim.x * 4;
  for (int row = row0; row < n; row += stride) {
    const float* p = in + (size_t)row * HID;
    float a = p[lane], c = p[lane + 64];
    float s = wave_allreduce_sum(a + c);
    float s2 = wave_allreduce_sum(a * a + c * c);
    float mean = s * (1.f / 128.f);
    float var = s2 * (1.f / 128.f) - mean * mean;
    float rs = rsqrtf(var + 1e-5f);
    u16* o = out + (size_t)row * HID;
    o[lane] = f2bf((a - mean) * rs * w[lane] + b[lane]);
    o[lane + 64] = f2bf((c - mean) * rs * w[lane + 64] + b[lane + 64]);
  }
}

// ---------- weight conversion + cnt zero-fill ----------
__global__ __launch_bounds__(256) void convert_weights(
    const float* __restrict__ Wq, const float* __restrict__ Wk,
    const float* __restrict__ Wv, const float* __restrict__ Ws,
    const float* __restrict__ W1, const float* __restrict__ W2,
    const float* __restrict__ We, u16* __restrict__ WqkvsT,
    u16* __restrict__ W1T, u16* __restrict__ W2T, u16* __restrict__ WbdT,
    int* __restrict__ cnt, int Nn) {
  int idx = blockIdx.x * 256 + threadIdx.x;
  if (idx < 65536) {
    int m = idx >> 7, k = idx & 127;
    const float* Wm = m < 128 ? Wq : m < 256 ? Wk : m < 384 ? Wv : Ws;
    WqkvsT[idx] = f2bf(Wm[k * 128 + (m & 127)]);
  } else if (idx < 131072) {
    int j = idx - 65536;
    int m = j >> 7, k = j & 127;
    W1T[j] = f2bf(W1[k * 512 + m]);
  } else if (idx < 196608) {
    int j = idx - 131072;
    int m = j >> 9, k = j & 511;
    W2T[j] = f2bf(W2[k * 128 + m]);
  } else if (idx < 229376) {
    int j = idx - 196608;  // WbdT [128][256]
    int m = j >> 8, c = j & 255;
    WbdT[j] = ((c >> 5) == (m >> 4)) ? f2bf(We[(c & 31) * 128 + m]) : (u16)0;
  } else if (idx < 229376 + Nn) {
    cnt[idx - 229376] = 0;
  }
}

// ---------- bf16 MFMA GEMM: tile 128x128, 4 waves, 2-phase double-buffered LDS ----------
#define GSTAGE(buf, kc)                                                        \
  {                                                                            \
    _Pragma("unroll") for (int i = 0; i < 2; i++) {                            \
      int idx = i * 256 + t;                                                   \
      int row = idx >> 2, c4 = idx & 3;                                        \
      __builtin_amdgcn_global_load_lds(                                        \
          (const __attribute__((address_space(1))) u32*)(A + (size_t)(r0 + row) * K + (kc) + c4 * 8), \
          (__attribute__((address_space(3))) u32*)&As[buf][idx * 8], 16, 0, 0);\
      __builtin_amdgcn_global_load_lds(                                        \
          (const __attribute__((address_space(1))) u32*)(Bt + (size_t)(c0 + row) * K + (kc) + c4 * 8), \
          (__attribute__((address_space(3))) u32*)&Bs[buf][idx * 8], 16, 0, 0);\
    }                                                                          \
  }

#define GEMM_CORE                                                              \
  constexpr int NT = K / 32;                                                   \
  GSTAGE(0, 0)                                                                 \
  __syncthreads();                                                             \
  _Pragma("unroll") for (int tt = 0; tt < NT; tt++) {                          \
    if (tt + 1 < NT) GSTAGE((tt + 1) & 1, (tt + 1) * 32)                       \
    bf16x8 a0 = *(const bf16x8*)&As[tt & 1][(w * 32 + sr) * 32 + g * 8];       \
    bf16x8 a1 = *(const bf16x8*)&As[tt & 1][(w * 32 + 16 + sr) * 32 + g * 8];  \
    _Pragma("unroll") for (int nn = 0; nn < 8; nn++) {                         \
      bf16x8 b = *(const bf16x8*)&Bs[tt & 1][(nn * 16 + sr) * 32 + g * 8];     \
      acc[0][nn] = __builtin_amdgcn_mfma_f32_16x16x32_bf16(a0, b, acc[0][nn], 0, 0, 0); \
      acc[1][nn] = __builtin_amdgcn_mfma_f32_16x16x32_bf16(a1, b, acc[1][nn], 0, 0, 0); \
    }                                                                          \
    __syncthreads();                                                           \
  }

// EPI: 0 = QKVS (y0->pq packed, y1/y2->pkv packed, y3->skip f32)
//      1 = GELU->bf16 ; 2 = +bias+addsrc->f32
template <int EPI, int K>
__global__ __launch_bounds__(256) void gemm_bf16(
    const u16* __restrict__ A, const u16* __restrict__ Bt, int n,
    const float* __restrict__ bias0, const float* __restrict__ bias1,
    const float* __restrict__ bias2, const float* __restrict__ bias3,
    float* __restrict__ of0, u32* __restrict__ opq, u32* __restrict__ pkv,
    u16* __restrict__ ob1, const float* __restrict__ addsrc) {
  __shared__ u16 As[2][128 * 32];
  __shared__ u16 Bs[2][128 * 32];
  int t = threadIdx.x;
  int w = t >> 6, lane = t & 63;
  int g = lane >> 4, sr = lane & 15;
  int r0 = blockIdx.x * 128;
  int c0 = blockIdx.y * 128;
  f32x4 acc[2][8];
#pragma unroll
  for (int m = 0; m < 2; m++)
#pragma unroll
    for (int nn = 0; nn < 8; nn++) acc[m][nn] = {0.f, 0.f, 0.f, 0.f};

  GEMM_CORE

  if (EPI == 0 && blockIdx.y == 0) {  // Q packed
#pragma unroll
    for (int m = 0; m < 2; m++)
#pragma unroll
      for (int nn = 0; nn < 4; nn++)
#pragma unroll
        for (int j = 0; j < 4; j++) {
          int row = r0 + w * 32 + m * 16 + g * 4 + j;
          if (row < n) {
            int cj = nn * 16 + sr;
            opq[((size_t)row << 6) + cj] =
                pack2(acc[m][nn][j] + bias0[cj], acc[m][nn + 4][j] + bias0[cj + 64]);
          }
        }
    return;
  }
  if (EPI == 0 && (blockIdx.y == 1 || blockIdx.y == 2)) {  // K/V packed
    const float* bp = blockIdx.y == 1 ? bias1 : bias2;
    int which = blockIdx.y - 1;
#pragma unroll
    for (int m = 0; m < 2; m++)
#pragma unroll
      for (int nn = 0; nn < 4; nn++)
#pragma unroll
        for (int j = 0; j < 4; j++) {
          int row = r0 + w * 32 + m * 16 + g * 4 + j;
          if (row < n) {
            int cj = nn * 16 + sr;
            pkv[((size_t)row << 7) + (cj << 1) + which] =
                pack2(acc[m][nn][j] + bp[cj], acc[m][nn + 4][j] + bp[cj + 64]);
          }
        }
    return;
  }
#pragma unroll
  for (int m = 0; m < 2; m++)
#pragma unroll
    for (int nn = 0; nn < 8; nn++)
#pragma unroll
      for (int j = 0; j < 4; j++) {
        int row = r0 + w * 32 + m * 16 + g * 4 + j;
        if (row < n) {
          int cj = nn * 16 + sr;
          float val = acc[m][nn][j];
          if (EPI == 0) {  // y==3: skip, f32
            of0[(size_t)row * HID + cj] = val + bias3[cj];
          } else if (EPI == 1) {
            int cjg = blockIdx.y * 128 + cj;
            float v2 = val + bias0[cjg];
            v2 = 0.5f * v2 * (1.f + erff(v2 * 0.70710678118f));
            ob1[(size_t)row * 512 + cjg] = f2bf(v2);
          } else {  // EPI == 2
            of0[(size_t)row * HID + cj] = val + bias0[cj] + addsrc[(size_t)row * HID + cj];
          }
        }
      }
}

// ---------- bd-GEMM (K=256) fused with finalize + LN2 ----------
__global__ __launch_bounds__(256) void gemm_bd_fin(
    const u16* __restrict__ A, const u16* __restrict__ Bt, int n,
    const float* __restrict__ x, const float* __restrict__ msg,
    const float* __restrict__ lbuf, const float* __restrict__ be,
    const float* __restrict__ lnw, const float* __restrict__ lnb,
    float* __restrict__ skipx1, u16* __restrict__ h2) {
  __shared__ u16 As[2][128 * 32];
  __shared__ u16 Bs[2][128 * 32];
  constexpr int K = 256;
  int t = threadIdx.x;
  int w = t >> 6, lane = t & 63;
  int g = lane >> 4, sr = lane & 15;
  int r0 = blockIdx.x * 128;
  int c0 = 0;
  f32x4 acc[2][8];
#pragma unroll
  for (int m = 0; m < 2; m++)
#pragma unroll
    for (int nn = 0; nn < 8; nn++) acc[m][nn] = {0.f, 0.f, 0.f, 0.f};

  GEMM_CORE

  float becol[8], wcol[8], bcol[8];
#pragma unroll
  for (int nn = 0; nn < 8; nn++) {
    int c = nn * 16 + sr;
    becol[nn] = be[c];
    wcol[nn] = lnw[c];
    bcol[nn] = lnb[c];
  }
#pragma unroll
  for (int m = 0; m < 2; m++)
#pragma unroll
    for (int j = 0; j < 4; j++) {
      int row = r0 + w * 32 + m * 16 + g * 4 + j;
      if (row < n) {
        const float* xr = x + (size_t)row * HID;
        const float* mr = msg + (size_t)row * HID;
        float* sxr = skipx1 + (size_t)row * HID;
        f32x4 L0 = *(const f32x4*)(lbuf + (size_t)row * 8);
        f32x4 L1 = *(const f32x4*)(lbuf + (size_t)row * 8 + 4);
        float tv[8];
        float s = 0.f, s2 = 0.f;
#pragma unroll
        for (int nn = 0; nn < 8; nn++) {
          int c = nn * 16 + sr;
          float linv = nn < 4 ? L0[nn] : L1[nn - 4];
          float t1 = xr[c] + (mr[c] + acc[m][nn][j]) * linv + becol[nn] + sxr[c];
          tv[nn] = t1;
          s += t1;
          s2 = fmaf(t1, t1, s2);
        }
        s = grp16_sum(s);
        s2 = grp16_sum(s2);
        float mean = s * (1.f / 128.f);
        float var = s2 * (1.f / 128.f) - mean * mean;
        float rs = rsqrtf(var + 1e-5f);
        u16* h2r = h2 + (size_t)row * HID;
#pragma unroll
        for (int nn = 0; nn < 8; nn++) {
          int c = nn * 16 + sr;
          sxr[c] = tv[nn];
          h2r[c] = f2bf((tv[nn] - mean) * rs * wcol[nn] + bcol[nn]);
        }
      }
    }
}

// ---------- counting sort by dst ----------
__global__ __launch_bounds__(256) void hist_kernel(const int* __restrict__ dstp,
                                                   int* __restrict__ cnt, int E) {
  int i = blockIdx.x * blockDim.x + threadIdx.x;
  int stride = gridDim.x * blockDim.x;
  for (; i < E; i += stride) atomicAdd(&cnt[dstp[i]], 1);
}

__global__ __launch_bounds__(256) void scan_partial(const int* __restrict__ cnt,
                                                    int* __restrict__ bs, int N) {
  __shared__ int sd[256];
  int idx = blockIdx.x * 256 + threadIdx.x;
  sd[threadIdx.x] = (idx < N) ? cnt[idx] : 0;
  __syncthreads();
  for (int s = 128; s > 0; s >>= 1) {
    if (threadIdx.x < s) sd[threadIdx.x] += sd[threadIdx.x + s];
    __syncthreads();
  }
  if (threadIdx.x == 0) bs[blockIdx.x] = sd[0];
}

__global__ __launch_bounds__(256) void scan_bs(const int* __restrict__ bs,
                                               int* __restrict__ bs2, int nb) {
  __shared__ int sd[256];
  int t = threadIdx.x;
  int v = (t < nb) ? bs[t] : 0;
  sd[t] = v;
  __syncthreads();
  for (int s = 1; s < 256; s <<= 1) {
    int add = (t >= s) ? sd[t - s] : 0;
    __syncthreads();
    sd[t] += add;
    __syncthreads();
  }
  bs2[t] = sd[t] - v;  // exclusive
}

__global__ __launch_bounds__(256) void scan_final(const int* __restrict__ cnt,
                                                  const int* __restrict__ bs2,
                                                  int* __restrict__ offs,
                                                  int* __restrict__ woff, int N) {
  __shared__ int sd[256];
  int t = threadIdx.x;
  int idx = blockIdx.x * 256 + t;
  int v = (idx < N) ? cnt[idx] : 0;
  sd[t] = v;
  __syncthreads();
  for (int s = 1; s < 256; s <<= 1) {
    int add = (t >= s) ? sd[t - s] : 0;
    __syncthreads();
    sd[t] += add;
    __syncthreads();
  }
  if (idx < N) {
    int ex = sd[t] - v + bs2[blockIdx.x];
    offs[idx] = ex;
    woff[idx] = ex;
  }
}

__global__ __launch_bounds__(256) void scatter_kernel(const int* __restrict__ ei,
                                                      int* __restrict__ woff,
                                                      int2* __restrict__ sorted,
                                                      int E) {
  int i = blockIdx.x * blockDim.x + threadIdx.x;
  int stride = gridDim.x * blockDim.x;
  for (; i < E; i += stride) {
    int src = ei[i];
    int dst = ei[E + i];
    int pos = atomicAdd(&woff[dst], 1);
    sorted[pos] = make_int2(src, i);
  }
}

// ---------- qWe precompute (grid-stride; LDS staged once per block) ----------
__global__ __launch_bounds__(256) void qwe_kernel(const u32* __restrict__ pq,
                                                  const float* __restrict__ We,
                                                  const float* __restrict__ be,
                                                  u32* __restrict__ qweb,
                                                  float* __restrict__ qbe, int Nn) {
  __shared__ float sWe[32][129];
  __shared__ float sbe[128];
  int t = threadIdx.x;
  for (int i = t; i < 32 * 128; i += 256) sWe[i >> 7][i & 127] = We[i];
  if (t < 128) sbe[t] = be[t];
  __syncthreads();
  int lane = t & 63, w = t >> 6;
  int g = lane >> 4, sr = lane & 15;
  int base = lane & 48;
  int stride = gridDim.x * 4;
  for (int node = blockIdx.x * 4 + w; node < Nn; node += stride) {
    u32 pw = pq[(size_t)node * 64 + lane];
    float q0 = bflo(pw), q1 = bfhi(pw);
    float o00 = 0.f, o01 = 0.f, o10 = 0.f, o11 = 0.f;
#pragma unroll
    for (int d0 = 0; d0 < 16; d0++) {
      float qa = __shfl(q0, base + d0);
      float qb = __shfl(q1, base + d0);
      int col = base + d0;
      o00 += qa * sWe[2 * sr][col];
      o01 += qa * sWe[2 * sr + 1][col];
      o10 += qb * sWe[2 * sr][64 + col];
      o11 += qb * sWe[2 * sr + 1][64 + col];
    }
    qweb[(size_t)node * 128 + g * 16 + sr] = pack2(o00 * SC, o01 * SC);
    qweb[(size_t)node * 128 + 64 + g * 16 + sr] = pack2(o10 * SC, o11 * SC);
    float t0 = grp16_sum(q0 * sbe[lane]);
    float t1 = grp16_sum(q1 * sbe[lane + 64]);
    if (sr == 0) {
      qbe[node * 8 + g] = t0 * SC;
      qbe[node * 8 + 4 + g] = t1 * SC;
    }
  }
}

// ---------- fused edge attention ----------
// ea read directly (f32, random 128B rows via eid readlane — each row touched once)
#define ISSUE4(P, base_)                                                       \
  {                                                                            \
    _Pragma("unroll") for (int jj = 0; jj < 4; jj++) {                         \
      int sj = min(base_ + jj, segn - 1);                                      \
      int sxx = __builtin_amdgcn_readlane(seRx, sj);                           \
      int syy = __builtin_amdgcn_readlane(seRy, sj);                           \
      P##kv[jj] = *(const u32x2*)(pkv + ((size_t)sxx << 7) + (lane << 1));     \
      P##ea[jj] = *(const float2*)(eaf + ((size_t)syy << 5) + 2 * sr);         \
    }                                                                          \
  }

#define COMP4(P, base_)                                                        \
  {                                                                            \
    _Pragma("unroll") for (int jj = 0; jj < 4; jj++) {                         \
      u32 kx = P##kv[jj].x, ky = P##kv[jj].y;                                  \
      float ex = P##ea[jj].x, ey = P##ea[jj].y;                                \
      float k0 = bflo(kx), k1 = bfhi(kx);                                      \
      float v0f = bflo(ky), v1f = bfhi(ky);                                    \
      float p0 = fmaf(q0C, k0, fmaf(qw0x, ex, qw0y * ey));                     \
      float p1 = fmaf(q1C, k1, fmaf(qw1x, ex, qw1y * ey));                     \
      p0 = grp16_sum(p0) + qb0C;                                               \
      p1 = grp16_sum(p1) + qb1C;                                               \
      bool val_ = (base_ + jj) < segn;                                         \
      float w1 = val_ ? __builtin_amdgcn_exp2f(p0) : 0.f;                      \
      float w2 = val_ ? __builtin_amdgcn_exp2f(p1) : 0.f;                      \
      l1 += w1;                                                                \
      l2 += w2;                                                                \
      a0 = fmaf(w1, v0f, a0);                                                  \
      a1 = fmaf(w2, v1f, a1);                                                  \
      wa00 = fmaf(w1, ex, wa00);                                               \
      wa01 = fmaf(w1, ey, wa01);                                               \
      wa10 = fmaf(w2, ex, wa10);                                               \
      wa11 = fmaf(w2, ey, wa11);                                               \
    }                                                                          \
  }

__global__ __launch_bounds__(256) void fused_edge(
    const int* __restrict__ offs, const int* __restrict__ cnt,
    const int2* __restrict__ sorted, const float* __restrict__ eaf,
    const float* __restrict__ be, const u32* __restrict__ pq,
    const u32* __restrict__ pkv, const u32* __restrict__ qweb,
    const float* __restrict__ qbe, float* __restrict__ msg,
    u32* __restrict__ weab, float* __restrict__ lbuf, int Nn, int Etot) {
  int lane = threadIdx.x & 63;
  int w = threadIdx.x >> 6;
  int g = lane >> 4, sr = lane & 15;
  int wid = blockIdx.x * 4 + w;
  int nw = gridDim.x * 4;
  int per = (Nn + nw - 1) / nw;
  int n0 = wid * per;
  int n1 = min(Nn, n0 + per);
  if (n0 >= n1) return;
  int nn = n1 - n0;

  float be0 = be[lane], be1 = be[lane + 64];

  int ml = min(lane, nn - 1);
  int myBeg = offs[n0 + ml];
  int myCnt = cnt[n0 + ml];

  // prefetch node 0 state
  int beg = __builtin_amdgcn_readlane(myBeg, 0);
  int num = __builtin_amdgcn_readlane(myCnt, 0);
  int2 se2 = sorted[min(beg + min(lane, max(num - 1, 0)), Etot - 1)];
  int seCx = se2.x, seCy = se2.y;
  u32 pqC = pq[(size_t)n0 * 64 + lane];
  u32 qwb0C = qweb[(size_t)n0 * 128 + g * 16 + sr];
  u32 qwb1C = qweb[(size_t)n0 * 128 + 64 + g * 16 + sr];
  float qb0C = qbe[(size_t)n0 * 8 + g], qb1C = qbe[(size_t)n0 * 8 + 4 + g];

  for (int ni = 0; ni < nn; ni++) {
    int node = n0 + ni;
    // next-node prefetch (independent of current compute)
    int begX = 0, numX = 0, seXx = 0, seXy = 0;
    u32 pqX = 0, qwb0X = 0, qwb1X = 0;
    float qb0X = 0.f, qb1X = 0.f;
    if (ni + 1 < nn) {
      begX = __builtin_amdgcn_readlane(myBeg, ni + 1);
      numX = __builtin_amdgcn_readlane(myCnt, ni + 1);
      int2 sx = sorted[min(begX + min(lane, max(numX - 1, 0)), Etot - 1)];
      seXx = sx.x;
      seXy = sx.y;
      pqX = pq[(size_t)(node + 1) * 64 + lane];
      qwb0X = qweb[(size_t)(node + 1) * 128 + g * 16 + sr];
      qwb1X = qweb[(size_t)(node + 1) * 128 + 64 + g * 16 + sr];
      qb0X = qbe[(size_t)(node + 1) * 8 + g];
      qb1X = qbe[(size_t)(node + 1) * 8 + 4 + g];
    }
    float q0C = bflo(pqC) * SC, q1C = bfhi(pqC) * SC;
    float qw0x = bflo(qwb0C), qw0y = bfhi(qwb0C);
    float qw1x = bflo(qwb1C), qw1y = bfhi(qwb1C);
    float l1 = 0.f, l2 = 0.f, a0 = 0.f, a1 = 0.f;
    float wa00 = 0.f, wa01 = 0.f, wa10 = 0.f, wa11 = 0.f;
    if (num > 0) {
      int cb = 0;
      int seRx = seCx, seRy = seCy;
      while (true) {
        int segn = min(num - cb, 64);
        u32x2 Akv[4], Bkv[4];
        float2 Aea[4], Bea[4];
        ISSUE4(A, 0)
        for (int c = 0; c < segn; c += 8) {
          ISSUE4(B, c + 4)
          COMP4(A, c)
          ISSUE4(A, c + 8)
          COMP4(B, c + 4)
        }
        cb += 64;
        if (cb >= num) break;
        int rem = num - cb;
        int2 sn = sorted[min(beg + cb + min(lane, rem - 1), Etot - 1)];
        seRx = sn.x;
        seRy = sn.y;
      }
    }
    size_t ob = (size_t)node * HID + lane;
    if (num > 0) {
      msg[ob] = a0;
      msg[ob + 64] = a1;
    } else {  // empty segment: bd_fin adds be -> cancel it
      msg[ob] = -be0;
      msg[ob + 64] = -be1;
    }
    weab[(size_t)node * 128 + g * 16 + sr] = pack2(wa00, wa01);
    weab[(size_t)node * 128 + 64 + g * 16 + sr] = pack2(wa10, wa11);
    if (sr == 0) {  // store reciprocals (bd_fin multiplies)
      lbuf[(size_t)node * 8 + g] = (num > 0) ? 1.f / (l1 + 1e-30f) : 1.f;
      lbuf[(size_t)node * 8 + 4 + g] = (num > 0) ? 1.f / (l2 + 1e-30f) : 1.f;
    }
    beg = begX;
    num = numX;
    seCx = seXx;
    seCy = seXy;
    pqC = pqX;
    qwb0C = qwb0X;
    qwb1C = qwb1X;
    qb0C = qb0X;
    qb1C = qb1X;
  }
}

extern "C" void kernel_launch(void* const* d_in, const int* in_sizes, int n_in,
                              void* d_out, int out_size, void* d_ws, size_t ws_size,
                              hipStream_t stream) {
  const float* x = (const float*)d_in[0];
  const int* ei = (const int*)d_in[1];
  const float* ea = (const float*)d_in[2];
  const float* Wq = (const float*)d_in[3];
  const float* bq = (const float*)d_in[4];
  const float* Wk = (const float*)d_in[5];
  const float* bk = (const float*)d_in[6];
  const float* Wv = (const float*)d_in[7];
  const float* bv = (const float*)d_in[8];
  const float* We = (const float*)d_in[9];
  const float* be = (const float*)d_in[10];
  const float* Wskip = (const float*)d_in[11];
  const float* bskip = (const float*)d_in[12];
  const float* ln1w = (const float*)d_in[13];
  const float* ln1b = (const float*)d_in[14];
  const float* W1 = (const float*)d_in[15];
  const float* b1p = (const float*)d_in[16];
  const float* W2 = (const float*)d_in[17];
  const float* b2p = (const float*)d_in[18];
  const float* ln2w = (const float*)d_in[19];
  const float* ln2b = (const float*)d_in[20];

  int N = in_sizes[0] / HID;
  int E = in_sizes[1] / 2;
  size_t nf = (size_t)N * HID;

  float* ws = (float*)d_ws;
  size_t off = 0;
  u16* h_bf = (u16*)(ws + off); off += nf / 2;
  u32* pq = (u32*)(ws + off); off += nf / 2;   // [node][64] packed q
  u32* pkv = (u32*)(ws + off); off += nf;      // [node][64]{kword,vword}
  float* skipx1 = ws + off; off += nf;         // skip, overwritten with x1
  float* msg = ws + off; off += nf;            // + weab below: aliased by tbf in FFN
  u32* weab = (u32*)(ws + off); off += nf;     // [node][128] packed bf16 pairs
  float* lbuf = ws + off; off += (size_t)N * 8;  // reciprocals
  u32* qweb = (u32*)(ws + off); off += nf;     // [node][128] packed bf16 qWe
  float* qbe = ws + off; off += (size_t)N * 8;
  int2* sorted = (int2*)(ws + off); off += (size_t)E * 2;  // {src, eid}
  int* cnt = (int*)(ws + off); off += N;
  int* offs = (int*)(ws + off); off += N;
  int* woff = (int*)(ws + off); off += N;
  int* bs = (int*)(ws + off); off += 256;
  int* bs2 = (int*)(ws + off); off += 256;
  u16* WqkvsT = (u16*)(ws + off); off += 32768;
  u16* W1T = (u16*)(ws + off); off += 32768;
  u16* W2T = (u16*)(ws + off); off += 32768;
  u16* WbdT = (u16*)(ws + off); off += 16384;
  u16* h2bf = h_bf;      // h_bf dead after QKVS GEMM
  u16* tbf = (u16*)msg;  // FFN intermediate aliases msg+weab (dead after bd_fin)

  convert_weights<<<1092, 256, 0, stream>>>(Wq, Wk, Wv, Wskip, W1, W2, We,
                                            WqkvsT, W1T, W2T, WbdT, cnt, N);

  int ln_blocks = (N + 3) / 4;
  ln_kernel<<<ln_blocks, 256, 0, stream>>>(x, h_bf, ln1w, ln1b, N);

  dim3 gq((N + 127) / 128, 4);
  gemm_bf16<0, 128><<<gq, 256, 0, stream>>>(h_bf, WqkvsT, N, bq, bk, bv, bskip,
                                            skipx1, pq, pkv, nullptr, nullptr);

  int nb = (N + 255) / 256;
  hist_kernel<<<1024, 256, 0, stream>>>(ei + E, cnt, E);
  scan_partial<<<nb, 256, 0, stream>>>(cnt, bs, N);
  scan_bs<<<1, 256, 0, stream>>>(bs, bs2, nb);
  scan_final<<<nb, 256, 0, stream>>>(cnt, bs2, offs, woff, N);
  scatter_kernel<<<1024, 256, 0, stream>>>(ei, woff, sorted, E);

  qwe_kernel<<<1024, 256, 0, stream>>>(pq, We, be, qweb, qbe, N);

  int fe_blocks = (N + 7) / 8;  // 4 waves/block, 2 nodes/wave
  fused_edge<<<fe_blocks, 256, 0, stream>>>(offs, cnt, sorted, ea, be, pq, pkv,
                                            qweb, qbe, msg, weab, lbuf, N, E);

  // bd-GEMM + finalize + LN2 fused
  dim3 ge((N + 127) / 128, 1);
  gemm_bd_fin<<<ge, 256, 0, stream>>>((const u16*)weab, WbdT, N, x, msg, lbuf,
                                      be, ln2w, ln2b, skipx1, h2bf);

  dim3 gf1((N + 127) / 128, 4);
  gemm_bf16<1, 128><<<gf1, 256, 0, stream>>>(h2bf, W1T, N, b1p, nullptr, nullptr,
                                             nullptr, nullptr, nullptr, nullptr,
                                             tbf, nullptr);
  dim3 gf2((N + 127) / 128, 1);
  gemm_bf16<2, 512><<<gf2, 256, 0, stream>>>(tbf, W2T, N, b2p, nullptr, nullptr,
                                             nullptr, (float*)d_out, nullptr,
                                             nullptr, nullptr, skipx1);
}